// Round 8
// baseline (360.581 us; speedup 1.0000x reference)
//
#include <hip/hip_runtime.h>
#include <hip/hip_bf16.h>
#include <cstdint>

#define E_ 32
#define H_ 1024
#define I_ 512
#define G_ 8
#define NSH_ 2
#define SCALE_ 2.5f
#define NROUTED (E_ * I_)            // 16384
#define PADCAP (16384 + E_ * 128)    // 20480, pad-to-128

typedef unsigned short u16;
using bf16x8_t = __attribute__((ext_vector_type(8))) __bf16;
using f32x4_t  = __attribute__((ext_vector_type(4))) float;

__device__ __forceinline__ u16 f2bf(float x) {
  union { float f; uint32_t u; } v; v.f = x;
  uint32_t u = v.u;
  uint32_t r = (u + 0x7fffu + ((u >> 16) & 1u)) >> 16;
  return (u16)r;
}
__device__ __forceinline__ float bf2f(u16 x) {
  union { uint32_t u; float f; } v; v.u = ((uint32_t)x) << 16; return v.f;
}

__device__ __forceinline__ void load_lds16(const void* g, void* l) {
  __builtin_amdgcn_global_load_lds(
      (const __attribute__((address_space(1))) unsigned int*)g,
      (__attribute__((address_space(3))) unsigned int*)l,
      16, 0, 0);
}

// u16-element offsets inside wbf: [bg | bu | bd | bshg | bshu | bshd]
#define OFF_BU   16777216L
#define OFF_BD   33554432L
#define OFF_BSHG 50331648L
#define OFF_BSHU 51380224L
#define OFF_BSHD 52428800L
#define WBF_TOT  53477376L

// ---------------- init: counters + lists + gw transpose + queues ------------
__global__ void init_kernel(const float* __restrict__ gw, float* __restrict__ gwT,
                            int* __restrict__ counts, int* __restrict__ cursor,
                            int* __restrict__ qheads,
                            int* __restrict__ tok_list, float* __restrict__ wt_list) {
  int i = blockIdx.x * blockDim.x + threadIdx.x;
  if (i < H_ * E_) {
    int k = i >> 5, e = i & 31;
    gwT[i] = gw[(long)e * H_ + k];
  }
  if (i < PADCAP) { tok_list[i] = 0; wt_list[i] = 0.f; }
  if (i < E_) { counts[i] = 0; cursor[i] = 0; }
  if (i < 2) qheads[i] = 0;
}

// ---------------- weights (p1 set) f32 -> bf16 ------------------------------
// converts wg, wu, shg, shu (8912896 float4 chunks)
__global__ void cvtw_kernel(const float* __restrict__ wg, const float* __restrict__ wu,
                            const float* __restrict__ shg, const float* __restrict__ shu,
                            u16* __restrict__ wbf) {
  long i = (long)blockIdx.x * blockDim.x + threadIdx.x;
  long stride = (long)gridDim.x * blockDim.x;
  for (; i < 8912896L; i += stride) {
    const float* s; long off; long dofs;
    if (i < 4194304L)      { s = wg;  off = i;            dofs = i * 4; }
    else if (i < 8388608L) { s = wu;  off = i - 4194304L; dofs = OFF_BU + off * 4; }
    else if (i < 8650752L) { s = shg; off = i - 8388608L; dofs = OFF_BSHG + off * 4; }
    else                   { s = shu; off = i - 8650752L; dofs = OFF_BSHU + off * 4; }
    float4 v = ((const float4*)s)[off];
    ushort4 o;
    o.x = f2bf(v.x); o.y = f2bf(v.y); o.z = f2bf(v.z); o.w = f2bf(v.w);
    *(ushort4*)(wbf + dofs) = o;
  }
}

// ---------------- router b: logits (f32 exact) + hs->bf16 -------------------
__global__ __launch_bounds__(256) void logits_kernel(
    const float* __restrict__ h, const float* __restrict__ gwT,
    float* __restrict__ logits, u16* __restrict__ hbf) {
  __shared__ float sh[8][H_];
  const int tid = threadIdx.x;
  const int t0 = blockIdx.x * 8;
  #pragma unroll
  for (int c = tid; c < 8 * H_ / 4; c += 256) {
    int row = c / (H_ / 4), col = c % (H_ / 4);
    float4 v = ((const float4*)(h + (size_t)(t0 + row) * H_))[col];
    ((float4*)sh[row])[col] = v;
    ushort4 o;
    o.x = f2bf(v.x); o.y = f2bf(v.y); o.z = f2bf(v.z); o.w = f2bf(v.w);
    ((ushort4*)(hbf + (size_t)(t0 + row) * H_))[col] = o;
  }
  __syncthreads();
  const int w = tid >> 6, l = tid & 63;
  const int e = l & 31, tl = w * 2 + (l >> 5);
  const float* hp = sh[tl];
  const float* wp = gwT + e;
  float acc = 0.f;
  #pragma unroll 8
  for (int k = 0; k < H_; ++k) acc += hp[k] * wp[(size_t)k * E_];
  logits[(size_t)(t0 + tl) * E_ + e] = acc;
}

// ---------------- router c: top-k (1 thread / token) ------------------------
__global__ __launch_bounds__(256) void topk_kernel(
    const float* __restrict__ logits, const float* __restrict__ gb,
    int* __restrict__ idx8, float* __restrict__ wt8, int* __restrict__ counts) {
  __shared__ float s_sc[256][33];
  const int lt = threadIdx.x;
  const int t = blockIdx.x * 256 + lt;
  float sc[E_];
  #pragma unroll
  for (int e = 0; e < E_; ++e) {
    float lg = logits[(size_t)t * E_ + e];
    float sig = 1.f / (1.f + __expf(-lg));
    s_sc[lt][e] = sig;
    sc[e] = sig + gb[e];
  }
  float gs[G_];
  #pragma unroll
  for (int g = 0; g < G_; ++g) {
    float a = sc[g * 4], b = sc[g * 4 + 1], c = sc[g * 4 + 2], d = sc[g * 4 + 3];
    float hi1 = fmaxf(a, b), lo1 = fminf(a, b);
    float hi2 = fmaxf(c, d), lo2 = fminf(c, d);
    float m1 = fmaxf(hi1, hi2);
    float m2 = (hi1 >= hi2) ? fmaxf(lo1, hi2) : fmaxf(lo2, hi1);
    gs[g] = m1 + m2;
  }
  unsigned gm = 0;
  #pragma unroll
  for (int r = 0; r < 4; ++r) {
    float bv = -1e30f; int bi = 0;
    #pragma unroll
    for (int g = 0; g < G_; ++g)
      if (!(gm & (1u << g)) && gs[g] > bv) { bv = gs[g]; bi = g; }
    gm |= 1u << bi;
  }
  float msk[E_];
  #pragma unroll
  for (int e = 0; e < E_; ++e)
    msk[e] = ((gm >> (e >> 2)) & 1u) ? sc[e] : 0.f;
  unsigned um = 0; float wsum = 0.f;
  int idxs[8]; float wts[8];
  #pragma unroll
  for (int r = 0; r < 8; ++r) {
    float bv = -1e30f; int bi = 0;
    #pragma unroll
    for (int e = 0; e < E_; ++e)
      if (!(um & (1u << e)) && msk[e] > bv) { bv = msk[e]; bi = e; }
    um |= 1u << bi;
    idxs[r] = bi;
    float wv = s_sc[lt][bi];
    wts[r] = wv; wsum += wv;
  }
  float inv = SCALE_ / (wsum + 1e-20f);
  #pragma unroll
  for (int r = 0; r < 8; ++r) {
    idx8[(size_t)t * 8 + r] = idxs[r];
    wt8[(size_t)t * 8 + r] = wts[r] * inv;
    atomicAdd(&counts[idxs[r]], 1);
  }
}

// ---------------- fill (inline padded scan) ----------------
__global__ void fill_kernel(const int* __restrict__ idx8, const float* __restrict__ wt8,
                            const int* __restrict__ counts, int* __restrict__ cursor,
                            int* __restrict__ tok_list, float* __restrict__ wt_list,
                            int* __restrict__ pair_pos, int npair) {
  int i = blockIdx.x * blockDim.x + threadIdx.x;
  if (i >= npair) return;
  int e = idx8[i];
  int offz = 0;
  for (int k = 0; k < E_; ++k) {
    if (k == e) break;
    offz += ((counts[k] + 127) >> 7) << 7;
  }
  int p = atomicAdd(&cursor[e], 1);
  int slot = offz + p;
  tok_list[slot] = i >> 3;
  wt_list[slot] = wt8[i];
  pair_pos[i] = slot;
}

// ---------------- phase 1: persistent gathered dual GEMM + fused wd cvt -----
// 1024 blocks x 256 thr (4 blk/CU). Tile 128 tok x 64 cols, swizzled LDS.
__global__ __launch_bounds__(256, 4) void p1_kernel(
    const u16* __restrict__ hbf,
    const u16* __restrict__ wbf,   // bg | bu | bd | bshg | bshu | bshd
    const int* __restrict__ counts,
    const int* __restrict__ tok_list, const float* __restrict__ wt_list,
    int* __restrict__ qheads,
    const float* __restrict__ wd, const float* __restrict__ shd,
    u16* __restrict__ wbf_mut,     // same as wbf, for bd/bshd writes
    u16* __restrict__ gu,          // [PADCAP][512]
    u16* __restrict__ gu_sh,       // [T][1024]
    int T) {
  __shared__ u16 lsA[128 * 64];
  __shared__ u16 lsB0[64 * 64];
  __shared__ u16 lsB1[64 * 64];
  __shared__ int s_tok[128];
  __shared__ float s_wt[128];
  __shared__ int s_cnt[E_], s_off[E_], s_ntt[E_];
  __shared__ int s_tot, s_tile;

  const int tid = threadIdx.x;
  if (tid < E_) s_cnt[tid] = counts[tid];
  __syncthreads();
  if (tid == 0) {
    int run = 0, tot = 0;
    for (int e = 0; e < E_; ++e) {
      s_off[e] = run;
      int nt = (s_cnt[e] + 127) >> 7;
      s_ntt[e] = nt;
      run += nt << 7;
      tot += nt * 8;
    }
    s_tot = tot + (T / 128) * 16;   // + shared-expert tiles
  }

  const int w = tid >> 6, l = tid & 63;
  const int wr = w >> 1, wc = w & 1;
  const int lr = l & 15, lh = l >> 4;
  const int sw = lr & 7;

  for (;;) {
    __syncthreads();
    if (tid == 0) s_tile = atomicAdd(&qheads[0], 1);
    __syncthreads();
    int q = s_tile;
    if (q >= s_tot) break;

    // map q -> (z, tt, nb)
    int z = 0, rem = q;
    for (; z < E_; ++z) { int t = s_ntt[z] * 8; if (rem < t) break; rem -= t; }
    const bool sh_e = (z == E_);
    int tt, nb;
    if (sh_e) { tt = rem >> 4; nb = rem & 15; }
    else      { tt = rem >> 3; nb = rem & 7; }
    const int off = sh_e ? 0 : s_off[z];

    if (tid < 128) {
      if (sh_e) { s_tok[tid] = tt * 128 + tid; s_wt[tid] = 1.0f; }
      else {
        int slot = off + tt * 128 + tid;
        s_tok[tid] = tok_list[slot];
        s_wt[tid] = wt_list[slot];
      }
    }
    __syncthreads();

    const u16* Bg = sh_e ? (wbf + OFF_BSHG + (size_t)(nb * 64) * H_)
                         : (wbf + ((size_t)z * I_ + nb * 64) * H_);
    const u16* Bu = sh_e ? (wbf + OFF_BSHU + (size_t)(nb * 64) * H_)
                         : (wbf + OFF_BU + ((size_t)z * I_ + nb * 64) * H_);

    f32x4_t acc0[4][2], acc1[4][2];
    #pragma unroll
    for (int m = 0; m < 4; ++m)
      #pragma unroll
      for (int n = 0; n < 2; ++n) {
        acc0[m][n] = (f32x4_t){0.f, 0.f, 0.f, 0.f};
        acc1[m][n] = (f32x4_t){0.f, 0.f, 0.f, 0.f};
      }

    for (int k0 = 0; k0 < H_; k0 += 64) {
      #pragma unroll
      for (int i = 0; i < 4; ++i) {
        int c = tid + 256 * i;
        int row = c >> 3, cb = c & 7;
        int scb = cb ^ (row & 7);
        load_lds16(hbf + (size_t)s_tok[row] * H_ + k0 + scb * 8, (char*)lsA + c * 16);
      }
      #pragma unroll
      for (int i = 0; i < 2; ++i) {
        int c = tid + 256 * i;
        int row = c >> 3, cb = c & 7;
        int scb = cb ^ (row & 7);
        load_lds16(Bg + (size_t)row * H_ + k0 + scb * 8, (char*)lsB0 + c * 16);
        load_lds16(Bu + (size_t)row * H_ + k0 + scb * 8, (char*)lsB1 + c * 16);
      }
      __syncthreads();
      #pragma unroll
      for (int kk = 0; kk < 64; kk += 32) {
        const int sb = kk >> 3;
        const int blk = ((sb + lh) ^ sw) << 3;
        bf16x8_t af[4], b0f[2], b1f[2];
        #pragma unroll
        for (int m = 0; m < 4; ++m)
          af[m] = *(const bf16x8_t*)(lsA + (wr * 64 + m * 16 + lr) * 64 + blk);
        #pragma unroll
        for (int n = 0; n < 2; ++n) {
          b0f[n] = *(const bf16x8_t*)(lsB0 + (wc * 32 + n * 16 + lr) * 64 + blk);
          b1f[n] = *(const bf16x8_t*)(lsB1 + (wc * 32 + n * 16 + lr) * 64 + blk);
        }
        #pragma unroll
        for (int m = 0; m < 4; ++m)
          #pragma unroll
          for (int n = 0; n < 2; ++n) {
            acc0[m][n] = __builtin_amdgcn_mfma_f32_16x16x32_bf16(af[m], b0f[n], acc0[m][n], 0, 0, 0);
            acc1[m][n] = __builtin_amdgcn_mfma_f32_16x16x32_bf16(af[m], b1f[n], acc1[m][n], 0, 0, 0);
          }
      }
      __syncthreads();
    }

    const int ldo = sh_e ? (I_ * NSH_) : I_;
    u16* outp = sh_e ? (gu_sh + (size_t)(tt * 128) * ldo + nb * 64)
                     : (gu + (size_t)(off + tt * 128) * ldo + nb * 64);
    #pragma unroll
    for (int m = 0; m < 4; ++m) {
      #pragma unroll
      for (int n = 0; n < 2; ++n) {
        int col = wc * 32 + n * 16 + lr;
        #pragma unroll
        for (int j = 0; j < 4; ++j) {
          int trow = wr * 64 + m * 16 + lh * 4 + j;
          float gv = acc0[m][n][j], uv = acc1[m][n][j];
          float sv = gv / (1.f + __expf(-gv));
          outp[(size_t)trow * ldo + col] = f2bf(sv * uv * s_wt[trow]);
        }
      }
    }
  }

  // fused wd/shd f32->bf16 conversion (p2 inputs), spread over all blocks
  const long WD4 = 4194304L, TOT4 = 4456448L;
  for (long i = (long)blockIdx.x * 256 + tid; i < TOT4; i += (long)gridDim.x * 256) {
    float4 v; long dofs;
    if (i < WD4) { v = ((const float4*)wd)[i]; dofs = OFF_BD + i * 4; }
    else { v = ((const float4*)shd)[i - WD4]; dofs = OFF_BSHD + (i - WD4) * 4; }
    ushort4 o;
    o.x = f2bf(v.x); o.y = f2bf(v.y); o.z = f2bf(v.z); o.w = f2bf(v.w);
    *(ushort4*)(wbf_mut + dofs) = o;
  }
}

// ---------------- phase 2: persistent gathered GEMM (down) ------------------
// 1536 blocks x 256 thr (6 blk/CU). Tile 128 pairs x 64 H-cols, swizzled LDS.
__global__ __launch_bounds__(256, 6) void p2_kernel(
    const u16* __restrict__ gu, const u16* __restrict__ gu_sh,
    const u16* __restrict__ wbf,
    const int* __restrict__ counts,
    int* __restrict__ qheads,
    u16* __restrict__ part,        // [PADCAP][H]
    u16* __restrict__ part_sh,     // [T][H]
    int T) {
  __shared__ u16 lsA[128 * 64];
  __shared__ u16 lsB[64 * 64];
  __shared__ int s_cnt[E_], s_off[E_], s_ntt[E_];
  __shared__ int s_tot, s_tile;

  const int tid = threadIdx.x;
  if (tid < E_) s_cnt[tid] = counts[tid];
  __syncthreads();
  if (tid == 0) {
    int run = 0, tot = 0;
    for (int e = 0; e < E_; ++e) {
      s_off[e] = run;
      int nt = (s_cnt[e] + 127) >> 7;
      s_ntt[e] = nt;
      run += nt << 7;
      tot += nt * 16;
    }
    s_tot = tot + (T / 128) * 16;
  }

  const int w = tid >> 6, l = tid & 63;
  const int wr = w >> 1, wc = w & 1;
  const int lr = l & 15, lh = l >> 4;
  const int sw = lr & 7;

  for (;;) {
    __syncthreads();
    if (tid == 0) s_tile = atomicAdd(&qheads[1], 1);
    __syncthreads();
    int q = s_tile;
    if (q >= s_tot) break;

    int z = 0, rem = q;
    for (; z < E_; ++z) { int t = s_ntt[z] * 16; if (rem < t) break; rem -= t; }
    const bool sh_e = (z == E_);
    int tt = rem >> 4, nb = rem & 15;

    const int K = sh_e ? (I_ * NSH_) : I_;
    const int NT = K / 64;
    const u16* Ab = sh_e ? (gu_sh + (size_t)(tt * 128) * K)
                         : (gu + (size_t)(s_off[z] + tt * 128) * K);
    const u16* Bb = sh_e ? (wbf + OFF_BSHD + (size_t)(nb * 64) * K)
                         : (wbf + OFF_BD + (size_t)z * H_ * I_ + (size_t)(nb * 64) * K);
    u16* outp = sh_e ? (part_sh + (size_t)(tt * 128) * H_ + nb * 64)
                     : (part + (size_t)(s_off[z] + tt * 128) * H_ + nb * 64);

    f32x4_t acc[4][2];
    #pragma unroll
    for (int m = 0; m < 4; ++m)
      #pragma unroll
      for (int n = 0; n < 2; ++n) acc[m][n] = (f32x4_t){0.f, 0.f, 0.f, 0.f};

    for (int s = 0; s < NT; ++s) {
      int k0 = s * 64;
      #pragma unroll
      for (int i = 0; i < 4; ++i) {
        int c = tid + 256 * i;
        int row = c >> 3, cb = c & 7;
        int scb = cb ^ (row & 7);
        load_lds16(Ab + (size_t)row * K + k0 + scb * 8, (char*)lsA + c * 16);
      }
      #pragma unroll
      for (int i = 0; i < 2; ++i) {
        int c = tid + 256 * i;
        int row = c >> 3, cb = c & 7;
        int scb = cb ^ (row & 7);
        load_lds16(Bb + (size_t)row * K + k0 + scb * 8, (char*)lsB + c * 16);
      }
      __syncthreads();
      #pragma unroll
      for (int kk = 0; kk < 64; kk += 32) {
        const int sb = kk >> 3;
        const int blk = ((sb + lh) ^ sw) << 3;
        bf16x8_t af[4], bf[2];
        #pragma unroll
        for (int m = 0; m < 4; ++m)
          af[m] = *(const bf16x8_t*)(lsA + (wr * 64 + m * 16 + lr) * 64 + blk);
        #pragma unroll
        for (int n = 0; n < 2; ++n)
          bf[n] = *(const bf16x8_t*)(lsB + (wc * 32 + n * 16 + lr) * 64 + blk);
        #pragma unroll
        for (int m = 0; m < 4; ++m)
          #pragma unroll
          for (int n = 0; n < 2; ++n)
            acc[m][n] = __builtin_amdgcn_mfma_f32_16x16x32_bf16(af[m], bf[n], acc[m][n], 0, 0, 0);
      }
      __syncthreads();
    }

    #pragma unroll
    for (int m = 0; m < 4; ++m) {
      #pragma unroll
      for (int n = 0; n < 2; ++n) {
        int col = wc * 32 + n * 16 + lr;
        #pragma unroll
        for (int j = 0; j < 4; ++j) {
          int trow = wr * 64 + m * 16 + lh * 4 + j;
          outp[(size_t)trow * H_ + col] = f2bf(acc[m][n][j]);
        }
      }
    }
  }
}

// ---------------- combine ----------------
__global__ void combine_kernel(const u16* __restrict__ part, const u16* __restrict__ part_sh,
                               const int* __restrict__ pair_pos, float* __restrict__ out) {
  int t = blockIdx.x;
  int h = threadIdx.x * 4;
  int pp[8];
  #pragma unroll
  for (int s = 0; s < 8; ++s) pp[s] = pair_pos[(long)t * 8 + s];
  ushort4 v = *(const ushort4*)(part_sh + (size_t)t * H_ + h);
  float a0 = bf2f(v.x), a1 = bf2f(v.y), a2 = bf2f(v.z), a3 = bf2f(v.w);
  #pragma unroll
  for (int s = 0; s < 8; ++s) {
    ushort4 u = *(const ushort4*)(part + (size_t)pp[s] * H_ + h);
    a0 += bf2f(u.x); a1 += bf2f(u.y); a2 += bf2f(u.z); a3 += bf2f(u.w);
  }
  float4 o = {a0, a1, a2, a3};
  *(float4*)(out + (size_t)t * H_ + h) = o;
}

extern "C" void kernel_launch(void* const* d_in, const int* in_sizes, int n_in,
                              void* d_out, int out_size, void* d_ws, size_t ws_size,
                              hipStream_t stream) {
  const float* hs  = (const float*)d_in[0];
  const float* gw  = (const float*)d_in[1];
  const float* gb  = (const float*)d_in[2];
  const float* wg  = (const float*)d_in[3];
  const float* wu  = (const float*)d_in[4];
  const float* wd  = (const float*)d_in[5];
  const float* shg = (const float*)d_in[6];
  const float* shu = (const float*)d_in[7];
  const float* shd = (const float*)d_in[8];
  float* out = (float*)d_out;

  const int T = in_sizes[0] / H_;  // 2048

  char* ws = (char*)d_ws;
  size_t off = 0;
  auto alloc = [&](size_t bytes) {
    char* p = ws + off;
    off += (bytes + 255) & ~(size_t)255;
    return p;
  };
  int*   counts   = (int*)alloc(E_ * 4);
  int*   cursor   = (int*)alloc(E_ * 4);
  int*   qheads   = (int*)alloc(2 * 4);
  int*   idx8     = (int*)alloc((size_t)T * 8 * 4);
  float* wt8      = (float*)alloc((size_t)T * 8 * 4);
  int*   pair_pos = (int*)alloc((size_t)T * 8 * 4);
  int*   tok_list = (int*)alloc(PADCAP * 4);
  float* wt_list  = (float*)alloc(PADCAP * 4);
  float* gwT      = (float*)alloc((size_t)H_ * E_ * 4);
  float* logits   = (float*)alloc((size_t)T * E_ * 4);
  u16* hbf     = (u16*)alloc((size_t)T * H_ * 2);
  u16* wbf     = (u16*)alloc((size_t)WBF_TOT * 2);
  u16* gu      = (u16*)alloc((size_t)PADCAP * I_ * 2);
  u16* gu_sh   = (u16*)alloc((size_t)T * I_ * NSH_ * 2);
  u16* part    = (u16*)alloc((size_t)PADCAP * H_ * 2);
  u16* part_sh = (u16*)alloc((size_t)T * H_ * 2);
  if (off > ws_size) return;

  hipLaunchKernelGGL(init_kernel, dim3(128), dim3(256), 0, stream,
                     gw, gwT, counts, cursor, qheads, tok_list, wt_list);

  hipLaunchKernelGGL(logits_kernel, dim3(T / 8), dim3(256), 0, stream,
                     hs, gwT, logits, hbf);
  hipLaunchKernelGGL(topk_kernel, dim3(T / 256), dim3(256), 0, stream,
                     logits, gb, idx8, wt8, counts);
  hipLaunchKernelGGL(fill_kernel, dim3((T * 8 + 255) / 256), dim3(256), 0, stream,
                     idx8, wt8, counts, cursor, tok_list, wt_list, pair_pos, T * 8);

  hipLaunchKernelGGL(cvtw_kernel, dim3(4096), dim3(256), 0, stream,
                     wg, wu, shg, shu, wbf);

  hipLaunchKernelGGL(p1_kernel, dim3(1024), dim3(256), 0, stream,
                     hbf, wbf, counts, tok_list, wt_list, qheads,
                     wd, shd, wbf, gu, gu_sh, T);

  hipLaunchKernelGGL(p2_kernel, dim3(1536), dim3(256), 0, stream,
                     gu, gu_sh, wbf, counts, qheads, part, part_sh, T);

  hipLaunchKernelGGL(combine_kernel, dim3(T), dim3(256), 0, stream,
                     part, part_sh, pair_pos, out);
}

// Round 9
// 326.524 us; speedup vs baseline: 1.1043x; 1.1043x over previous
//
#include <hip/hip_runtime.h>
#include <hip/hip_bf16.h>
#include <cstdint>

#define E_ 32
#define H_ 1024
#define I_ 512
#define G_ 8
#define NSH_ 2
#define SCALE_ 2.5f
#define NROUTED (E_ * I_)            // 16384
#define PADCAP (16384 + E_ * 128)    // 20480, pad-to-128

typedef unsigned short u16;
using bf16x8_t = __attribute__((ext_vector_type(8))) __bf16;
using f32x4_t  = __attribute__((ext_vector_type(4))) float;

__device__ __forceinline__ u16 f2bf(float x) {
  union { float f; uint32_t u; } v; v.f = x;
  uint32_t u = v.u;
  uint32_t r = (u + 0x7fffu + ((u >> 16) & 1u)) >> 16;
  return (u16)r;
}
__device__ __forceinline__ float bf2f(u16 x) {
  union { uint32_t u; float f; } v; v.u = ((uint32_t)x) << 16; return v.f;
}

__device__ __forceinline__ void load_lds16(const void* g, void* l) {
  __builtin_amdgcn_global_load_lds(
      (const __attribute__((address_space(1))) unsigned int*)g,
      (__attribute__((address_space(3))) unsigned int*)l,
      16, 0, 0);
}

// u16-element offsets inside wbf: [bg | bu | bd | bshg | bshu | bshd]
#define OFF_BU   16777216L
#define OFF_BD   33554432L
#define OFF_BSHG 50331648L
#define OFF_BSHU 51380224L
#define OFF_BSHD 52428800L
#define WBF_TOT  53477376L

// ---------------- init: counters + lists + gw transpose + queues ------------
__global__ void init_kernel(const float* __restrict__ gw, float* __restrict__ gwT,
                            int* __restrict__ counts, int* __restrict__ cursor,
                            int* __restrict__ qheads,
                            int* __restrict__ tok_list, float* __restrict__ wt_list) {
  int i = blockIdx.x * blockDim.x + threadIdx.x;
  if (i < H_ * E_) {
    int k = i >> 5, e = i & 31;
    gwT[i] = gw[(long)e * H_ + k];
  }
  if (i < PADCAP) { tok_list[i] = 0; wt_list[i] = 0.f; }
  if (i < E_) { counts[i] = 0; cursor[i] = 0; }
  if (i < 2) qheads[i] = 0;
}

// ---------------- all weights f32 -> bf16 ------------------------------------
#define W4_WG  4194304L
#define W4_WU  8388608L
#define W4_WD  12582912L
#define W4_SHG 12845056L
#define W4_SHU 13107200L
#define W4_TOT 13369344L
__global__ void cvtw_kernel(const float* __restrict__ wg, const float* __restrict__ wu,
                            const float* __restrict__ wd, const float* __restrict__ shg,
                            const float* __restrict__ shu, const float* __restrict__ shd,
                            u16* __restrict__ wbf) {
  long i = (long)blockIdx.x * blockDim.x + threadIdx.x;
  long stride = (long)gridDim.x * blockDim.x;
  for (; i < W4_TOT; i += stride) {
    const float* s; long off; long dofs;
    if (i < W4_WG)       { s = wg;  off = i;            dofs = off * 4; }
    else if (i < W4_WU)  { s = wu;  off = i - W4_WG;    dofs = OFF_BU + off * 4; }
    else if (i < W4_WD)  { s = wd;  off = i - W4_WU;    dofs = OFF_BD + off * 4; }
    else if (i < W4_SHG) { s = shg; off = i - W4_WD;    dofs = OFF_BSHG + off * 4; }
    else if (i < W4_SHU) { s = shu; off = i - W4_SHG;   dofs = OFF_BSHU + off * 4; }
    else                 { s = shd; off = i - W4_SHU;   dofs = OFF_BSHD + off * 4; }
    float4 v = ((const float4*)s)[off];
    ushort4 o;
    o.x = f2bf(v.x); o.y = f2bf(v.y); o.z = f2bf(v.z); o.w = f2bf(v.w);
    *(ushort4*)(wbf + dofs) = o;
  }
}

// ---------------- router b: logits (f32 exact) + hs->bf16 -------------------
__global__ __launch_bounds__(256) void logits_kernel(
    const float* __restrict__ h, const float* __restrict__ gwT,
    float* __restrict__ logits, u16* __restrict__ hbf) {
  __shared__ float sh[8][H_];
  const int tid = threadIdx.x;
  const int t0 = blockIdx.x * 8;
  #pragma unroll
  for (int c = tid; c < 8 * H_ / 4; c += 256) {
    int row = c / (H_ / 4), col = c % (H_ / 4);
    float4 v = ((const float4*)(h + (size_t)(t0 + row) * H_))[col];
    ((float4*)sh[row])[col] = v;
    ushort4 o;
    o.x = f2bf(v.x); o.y = f2bf(v.y); o.z = f2bf(v.z); o.w = f2bf(v.w);
    ((ushort4*)(hbf + (size_t)(t0 + row) * H_))[col] = o;
  }
  __syncthreads();
  const int w = tid >> 6, l = tid & 63;
  const int e = l & 31, tl = w * 2 + (l >> 5);
  const float* hp = sh[tl];
  const float* wp = gwT + e;
  float acc = 0.f;
  #pragma unroll 8
  for (int k = 0; k < H_; ++k) acc += hp[k] * wp[(size_t)k * E_];
  logits[(size_t)(t0 + tl) * E_ + e] = acc;
}

// ---------------- router c: top-k (1 thread / token) ------------------------
__global__ __launch_bounds__(256) void topk_kernel(
    const float* __restrict__ logits, const float* __restrict__ gb,
    int* __restrict__ idx8, float* __restrict__ wt8, int* __restrict__ counts) {
  __shared__ float s_sc[256][33];
  const int lt = threadIdx.x;
  const int t = blockIdx.x * 256 + lt;
  float sc[E_];
  #pragma unroll
  for (int e = 0; e < E_; ++e) {
    float lg = logits[(size_t)t * E_ + e];
    float sig = 1.f / (1.f + __expf(-lg));
    s_sc[lt][e] = sig;
    sc[e] = sig + gb[e];
  }
  float gs[G_];
  #pragma unroll
  for (int g = 0; g < G_; ++g) {
    float a = sc[g * 4], b = sc[g * 4 + 1], c = sc[g * 4 + 2], d = sc[g * 4 + 3];
    float hi1 = fmaxf(a, b), lo1 = fminf(a, b);
    float hi2 = fmaxf(c, d), lo2 = fminf(c, d);
    float m1 = fmaxf(hi1, hi2);
    float m2 = (hi1 >= hi2) ? fmaxf(lo1, hi2) : fmaxf(lo2, hi1);
    gs[g] = m1 + m2;
  }
  unsigned gm = 0;
  #pragma unroll
  for (int r = 0; r < 4; ++r) {
    float bv = -1e30f; int bi = 0;
    #pragma unroll
    for (int g = 0; g < G_; ++g)
      if (!(gm & (1u << g)) && gs[g] > bv) { bv = gs[g]; bi = g; }
    gm |= 1u << bi;
  }
  float msk[E_];
  #pragma unroll
  for (int e = 0; e < E_; ++e)
    msk[e] = ((gm >> (e >> 2)) & 1u) ? sc[e] : 0.f;
  unsigned um = 0; float wsum = 0.f;
  int idxs[8]; float wts[8];
  #pragma unroll
  for (int r = 0; r < 8; ++r) {
    float bv = -1e30f; int bi = 0;
    #pragma unroll
    for (int e = 0; e < E_; ++e)
      if (!(um & (1u << e)) && msk[e] > bv) { bv = msk[e]; bi = e; }
    um |= 1u << bi;
    idxs[r] = bi;
    float wv = s_sc[lt][bi];
    wts[r] = wv; wsum += wv;
  }
  float inv = SCALE_ / (wsum + 1e-20f);
  #pragma unroll
  for (int r = 0; r < 8; ++r) {
    idx8[(size_t)t * 8 + r] = idxs[r];
    wt8[(size_t)t * 8 + r] = wts[r] * inv;
    atomicAdd(&counts[idxs[r]], 1);
  }
}

// ---------------- fill (inline padded scan) ----------------
__global__ void fill_kernel(const int* __restrict__ idx8, const float* __restrict__ wt8,
                            const int* __restrict__ counts, int* __restrict__ cursor,
                            int* __restrict__ tok_list, float* __restrict__ wt_list,
                            int* __restrict__ pair_pos, int npair) {
  int i = blockIdx.x * blockDim.x + threadIdx.x;
  if (i >= npair) return;
  int e = idx8[i];
  int offz = 0;
  for (int k = 0; k < E_; ++k) {
    if (k == e) break;
    offz += ((counts[k] + 127) >> 7) << 7;
  }
  int p = atomicAdd(&cursor[e], 1);
  int slot = offz + p;
  tok_list[slot] = i >> 3;
  wt_list[slot] = wt8[i];
  pair_pos[i] = slot;
}

// ---------------- phase 1: persistent gathered dual GEMM, 128x128 -----------
// 512 blocks x 256 thr (2 blk/CU). Tile 128 tok x 128 cols, swizzled LDS.
__global__ __launch_bounds__(256, 2) void p1_kernel(
    const u16* __restrict__ hbf,
    const u16* __restrict__ wbf,
    const int* __restrict__ counts,
    const int* __restrict__ tok_list, const float* __restrict__ wt_list,
    int* __restrict__ qheads,
    u16* __restrict__ gu,          // [PADCAP][512]
    u16* __restrict__ gu_sh,       // [T][1024]
    int T) {
  __shared__ u16 lsA[128 * 64];
  __shared__ u16 lsB0[128 * 64];
  __shared__ u16 lsB1[128 * 64];
  __shared__ int s_tok[128];
  __shared__ float s_wt[128];
  __shared__ int s_off[E_], s_ntt[E_];
  __shared__ int s_tot, s_tile;

  const int tid = threadIdx.x;
  if (tid == 0) {
    int run = 0, tot = 0;
    for (int e = 0; e < E_; ++e) {
      s_off[e] = run;
      int nt = (counts[e] + 127) >> 7;
      s_ntt[e] = nt;
      run += nt << 7;
      tot += nt * 4;                 // 4 nb (128-col) per tt
    }
    s_tot = tot + (T / 128) * 8;     // shared: 16 tt x 8 nb
  }

  const int w = tid >> 6, l = tid & 63;
  const int wr = w >> 1, wc = w & 1;
  const int lr = l & 15, lh = l >> 4;
  const int sw = lr & 7;

  for (;;) {
    __syncthreads();
    if (tid == 0) s_tile = atomicAdd(&qheads[0], 1);
    __syncthreads();
    int q = s_tile;
    if (q >= s_tot) break;

    int z = 0, rem = q;
    for (; z < E_; ++z) { int t = s_ntt[z] * 4; if (rem < t) break; rem -= t; }
    const bool sh_e = (z == E_);
    int tt, nb;
    if (sh_e) { tt = rem >> 3; nb = rem & 7; }
    else      { tt = rem >> 2; nb = rem & 3; }
    const int off = sh_e ? 0 : s_off[z];

    if (tid < 128) {
      if (sh_e) { s_tok[tid] = tt * 128 + tid; s_wt[tid] = 1.0f; }
      else {
        int slot = off + tt * 128 + tid;
        s_tok[tid] = tok_list[slot];
        s_wt[tid] = wt_list[slot];
      }
    }
    __syncthreads();

    const u16* Bg = sh_e ? (wbf + OFF_BSHG + (size_t)(nb * 128) * H_)
                         : (wbf + ((size_t)z * I_ + nb * 128) * H_);
    const u16* Bu = sh_e ? (wbf + OFF_BSHU + (size_t)(nb * 128) * H_)
                         : (wbf + OFF_BU + ((size_t)z * I_ + nb * 128) * H_);

    f32x4_t acc0[4][4], acc1[4][4];
    #pragma unroll
    for (int m = 0; m < 4; ++m)
      #pragma unroll
      for (int n = 0; n < 4; ++n) {
        acc0[m][n] = (f32x4_t){0.f, 0.f, 0.f, 0.f};
        acc1[m][n] = (f32x4_t){0.f, 0.f, 0.f, 0.f};
      }

    for (int k0 = 0; k0 < H_; k0 += 64) {
      #pragma unroll
      for (int i = 0; i < 4; ++i) {
        int c = tid + 256 * i;
        int row = c >> 3, cb = c & 7;
        int scb = cb ^ (row & 7);
        load_lds16(hbf + (size_t)s_tok[row] * H_ + k0 + scb * 8, (char*)lsA + c * 16);
        load_lds16(Bg + (size_t)row * H_ + k0 + scb * 8, (char*)lsB0 + c * 16);
        load_lds16(Bu + (size_t)row * H_ + k0 + scb * 8, (char*)lsB1 + c * 16);
      }
      __syncthreads();
      #pragma unroll
      for (int kk = 0; kk < 64; kk += 32) {
        const int sb = kk >> 3;
        const int blk = ((sb + lh) ^ sw) << 3;
        bf16x8_t af[4], b0f[4], b1f[4];
        #pragma unroll
        for (int m = 0; m < 4; ++m)
          af[m] = *(const bf16x8_t*)(lsA + (wr * 64 + m * 16 + lr) * 64 + blk);
        #pragma unroll
        for (int n = 0; n < 4; ++n) {
          b0f[n] = *(const bf16x8_t*)(lsB0 + (wc * 64 + n * 16 + lr) * 64 + blk);
          b1f[n] = *(const bf16x8_t*)(lsB1 + (wc * 64 + n * 16 + lr) * 64 + blk);
        }
        #pragma unroll
        for (int m = 0; m < 4; ++m)
          #pragma unroll
          for (int n = 0; n < 4; ++n) {
            acc0[m][n] = __builtin_amdgcn_mfma_f32_16x16x32_bf16(af[m], b0f[n], acc0[m][n], 0, 0, 0);
            acc1[m][n] = __builtin_amdgcn_mfma_f32_16x16x32_bf16(af[m], b1f[n], acc1[m][n], 0, 0, 0);
          }
      }
      __syncthreads();
    }

    const int ldo = sh_e ? (I_ * NSH_) : I_;
    u16* outp = sh_e ? (gu_sh + (size_t)(tt * 128) * ldo + nb * 128)
                     : (gu + (size_t)(off + tt * 128) * ldo + nb * 128);
    #pragma unroll
    for (int m = 0; m < 4; ++m) {
      #pragma unroll
      for (int n = 0; n < 4; ++n) {
        int col = wc * 64 + n * 16 + lr;
        #pragma unroll
        for (int j = 0; j < 4; ++j) {
          int trow = wr * 64 + m * 16 + lh * 4 + j;
          float gv = acc0[m][n][j], uv = acc1[m][n][j];
          float sv = gv / (1.f + __expf(-gv));
          outp[(size_t)trow * ldo + col] = f2bf(sv * uv * s_wt[trow]);
        }
      }
    }
  }
}

// ---------------- phase 2: persistent gathered GEMM (down), 128x128 ---------
// 768 blocks x 256 thr (3 blk/CU). Tile 128 pairs x 128 H-cols, swizzled LDS.
__global__ __launch_bounds__(256, 3) void p2_kernel(
    const u16* __restrict__ gu, const u16* __restrict__ gu_sh,
    const u16* __restrict__ wbf,
    const int* __restrict__ counts,
    int* __restrict__ qheads,
    u16* __restrict__ part,        // [PADCAP][H]
    u16* __restrict__ part_sh,     // [T][H]
    int T) {
  __shared__ u16 lsA[128 * 64];
  __shared__ u16 lsB[128 * 64];
  __shared__ int s_off[E_], s_ntt[E_];
  __shared__ int s_tot, s_tile;

  const int tid = threadIdx.x;
  if (tid == 0) {
    int run = 0, tot = 0;
    for (int e = 0; e < E_; ++e) {
      s_off[e] = run;
      int nt = (counts[e] + 127) >> 7;
      s_ntt[e] = nt;
      run += nt << 7;
      tot += nt * 8;                 // 8 nb (128-col) per tt
    }
    s_tot = tot + (T / 128) * 8;
  }

  const int w = tid >> 6, l = tid & 63;
  const int wr = w >> 1, wc = w & 1;
  const int lr = l & 15, lh = l >> 4;
  const int sw = lr & 7;

  for (;;) {
    __syncthreads();
    if (tid == 0) s_tile = atomicAdd(&qheads[1], 1);
    __syncthreads();
    int q = s_tile;
    if (q >= s_tot) break;

    int z = 0, rem = q;
    for (; z < E_; ++z) { int t = s_ntt[z] * 8; if (rem < t) break; rem -= t; }
    const bool sh_e = (z == E_);
    int tt = rem >> 3, nb = rem & 7;

    const int K = sh_e ? (I_ * NSH_) : I_;
    const int NT = K / 64;
    const u16* Ab = sh_e ? (gu_sh + (size_t)(tt * 128) * K)
                         : (gu + (size_t)(s_off[z] + tt * 128) * K);
    const u16* Bb = sh_e ? (wbf + OFF_BSHD + (size_t)(nb * 128) * K)
                         : (wbf + OFF_BD + (size_t)z * H_ * I_ + (size_t)(nb * 128) * K);
    u16* outp = sh_e ? (part_sh + (size_t)(tt * 128) * H_ + nb * 128)
                     : (part + (size_t)(s_off[z] + tt * 128) * H_ + nb * 128);

    f32x4_t acc[4][4];
    #pragma unroll
    for (int m = 0; m < 4; ++m)
      #pragma unroll
      for (int n = 0; n < 4; ++n) acc[m][n] = (f32x4_t){0.f, 0.f, 0.f, 0.f};

    for (int s = 0; s < NT; ++s) {
      int k0 = s * 64;
      #pragma unroll
      for (int i = 0; i < 4; ++i) {
        int c = tid + 256 * i;
        int row = c >> 3, cb = c & 7;
        int scb = cb ^ (row & 7);
        load_lds16(Ab + (size_t)row * K + k0 + scb * 8, (char*)lsA + c * 16);
        load_lds16(Bb + (size_t)row * K + k0 + scb * 8, (char*)lsB + c * 16);
      }
      __syncthreads();
      #pragma unroll
      for (int kk = 0; kk < 64; kk += 32) {
        const int sb = kk >> 3;
        const int blk = ((sb + lh) ^ sw) << 3;
        bf16x8_t af[4], bf[4];
        #pragma unroll
        for (int m = 0; m < 4; ++m)
          af[m] = *(const bf16x8_t*)(lsA + (wr * 64 + m * 16 + lr) * 64 + blk);
        #pragma unroll
        for (int n = 0; n < 4; ++n)
          bf[n] = *(const bf16x8_t*)(lsB + (wc * 64 + n * 16 + lr) * 64 + blk);
        #pragma unroll
        for (int m = 0; m < 4; ++m)
          #pragma unroll
          for (int n = 0; n < 4; ++n)
            acc[m][n] = __builtin_amdgcn_mfma_f32_16x16x32_bf16(af[m], bf[n], acc[m][n], 0, 0, 0);
      }
      __syncthreads();
    }

    #pragma unroll
    for (int m = 0; m < 4; ++m) {
      #pragma unroll
      for (int n = 0; n < 4; ++n) {
        int col = wc * 64 + n * 16 + lr;
        #pragma unroll
        for (int j = 0; j < 4; ++j) {
          int trow = wr * 64 + m * 16 + lh * 4 + j;
          outp[(size_t)trow * H_ + col] = f2bf(acc[m][n][j]);
        }
      }
    }
  }
}

// ---------------- combine ----------------
__global__ void combine_kernel(const u16* __restrict__ part, const u16* __restrict__ part_sh,
                               const int* __restrict__ pair_pos, float* __restrict__ out) {
  int t = blockIdx.x;
  int h = threadIdx.x * 4;
  int pp[8];
  #pragma unroll
  for (int s = 0; s < 8; ++s) pp[s] = pair_pos[(long)t * 8 + s];
  ushort4 v = *(const ushort4*)(part_sh + (size_t)t * H_ + h);
  float a0 = bf2f(v.x), a1 = bf2f(v.y), a2 = bf2f(v.z), a3 = bf2f(v.w);
  #pragma unroll
  for (int s = 0; s < 8; ++s) {
    ushort4 u = *(const ushort4*)(part + (size_t)pp[s] * H_ + h);
    a0 += bf2f(u.x); a1 += bf2f(u.y); a2 += bf2f(u.z); a3 += bf2f(u.w);
  }
  float4 o = {a0, a1, a2, a3};
  *(float4*)(out + (size_t)t * H_ + h) = o;
}

extern "C" void kernel_launch(void* const* d_in, const int* in_sizes, int n_in,
                              void* d_out, int out_size, void* d_ws, size_t ws_size,
                              hipStream_t stream) {
  const float* hs  = (const float*)d_in[0];
  const float* gw  = (const float*)d_in[1];
  const float* gb  = (const float*)d_in[2];
  const float* wg  = (const float*)d_in[3];
  const float* wu  = (const float*)d_in[4];
  const float* wd  = (const float*)d_in[5];
  const float* shg = (const float*)d_in[6];
  const float* shu = (const float*)d_in[7];
  const float* shd = (const float*)d_in[8];
  float* out = (float*)d_out;

  const int T = in_sizes[0] / H_;  // 2048

  char* ws = (char*)d_ws;
  size_t off = 0;
  auto alloc = [&](size_t bytes) {
    char* p = ws + off;
    off += (bytes + 255) & ~(size_t)255;
    return p;
  };
  int*   counts   = (int*)alloc(E_ * 4);
  int*   cursor   = (int*)alloc(E_ * 4);
  int*   qheads   = (int*)alloc(2 * 4);
  int*   idx8     = (int*)alloc((size_t)T * 8 * 4);
  float* wt8      = (float*)alloc((size_t)T * 8 * 4);
  int*   pair_pos = (int*)alloc((size_t)T * 8 * 4);
  int*   tok_list = (int*)alloc(PADCAP * 4);
  float* wt_list  = (float*)alloc(PADCAP * 4);
  float* gwT      = (float*)alloc((size_t)H_ * E_ * 4);
  float* logits   = (float*)alloc((size_t)T * E_ * 4);
  u16* hbf     = (u16*)alloc((size_t)T * H_ * 2);
  u16* wbf     = (u16*)alloc((size_t)WBF_TOT * 2);
  u16* gu      = (u16*)alloc((size_t)PADCAP * I_ * 2);
  u16* gu_sh   = (u16*)alloc((size_t)T * I_ * NSH_ * 2);
  u16* part    = (u16*)alloc((size_t)PADCAP * H_ * 2);
  u16* part_sh = (u16*)alloc((size_t)T * H_ * 2);
  if (off > ws_size) return;

  hipLaunchKernelGGL(init_kernel, dim3(128), dim3(256), 0, stream,
                     gw, gwT, counts, cursor, qheads, tok_list, wt_list);

  hipLaunchKernelGGL(logits_kernel, dim3(T / 8), dim3(256), 0, stream,
                     hs, gwT, logits, hbf);
  hipLaunchKernelGGL(topk_kernel, dim3(T / 256), dim3(256), 0, stream,
                     logits, gb, idx8, wt8, counts);
  hipLaunchKernelGGL(fill_kernel, dim3((T * 8 + 255) / 256), dim3(256), 0, stream,
                     idx8, wt8, counts, cursor, tok_list, wt_list, pair_pos, T * 8);

  hipLaunchKernelGGL(cvtw_kernel, dim3(4096), dim3(256), 0, stream,
                     wg, wu, wd, shg, shu, shd, wbf);

  hipLaunchKernelGGL(p1_kernel, dim3(512), dim3(256), 0, stream,
                     hbf, wbf, counts, tok_list, wt_list, qheads, gu, gu_sh, T);

  hipLaunchKernelGGL(p2_kernel, dim3(768), dim3(256), 0, stream,
                     gu, gu_sh, wbf, counts, qheads, part, part_sh, T);

  hipLaunchKernelGGL(combine_kernel, dim3(T), dim3(256), 0, stream,
                     part, part_sh, pair_pos, out);
}

// Round 10
// 309.178 us; speedup vs baseline: 1.1663x; 1.0561x over previous
//
#include <hip/hip_runtime.h>
#include <hip/hip_bf16.h>
#include <cstdint>

#define E_ 32
#define H_ 1024
#define I_ 512
#define G_ 8
#define NSH_ 2
#define SCALE_ 2.5f
#define NROUTED (E_ * I_)            // 16384
#define PADCAP (16384 + E_ * 128)    // 20480, pad-to-128

typedef unsigned short u16;
using bf16x8_t = __attribute__((ext_vector_type(8))) __bf16;
using f32x4_t  = __attribute__((ext_vector_type(4))) float;

__device__ __forceinline__ u16 f2bf(float x) {
  union { float f; uint32_t u; } v; v.f = x;
  uint32_t u = v.u;
  uint32_t r = (u + 0x7fffu + ((u >> 16) & 1u)) >> 16;
  return (u16)r;
}
__device__ __forceinline__ float bf2f(u16 x) {
  union { uint32_t u; float f; } v; v.u = ((uint32_t)x) << 16; return v.f;
}

__device__ __forceinline__ void load_lds16(const void* g, void* l) {
  __builtin_amdgcn_global_load_lds(
      (const __attribute__((address_space(1))) unsigned int*)g,
      (__attribute__((address_space(3))) unsigned int*)l,
      16, 0, 0);
}

// u16-element offsets inside wbf: [bg | bu | bd | bshg | bshu | bshd]
#define OFF_BU   16777216L
#define OFF_BD   33554432L
#define OFF_BSHG 50331648L
#define OFF_BSHU 51380224L
#define OFF_BSHD 52428800L
#define WBF_TOT  53477376L

// ---------------- prep: init + gw transpose + all-weight f32->bf16 ----------
#define W4_WG  4194304L
#define W4_WU  8388608L
#define W4_WD  12582912L
#define W4_SHG 12845056L
#define W4_SHU 13107200L
#define W4_TOT 13369344L
__global__ void prep_kernel(const float* __restrict__ gw, float* __restrict__ gwT,
                            int* __restrict__ counts, int* __restrict__ cursor,
                            int* __restrict__ qheads,
                            int* __restrict__ tok_list, float* __restrict__ wt_list,
                            const float* __restrict__ wg, const float* __restrict__ wu,
                            const float* __restrict__ wd, const float* __restrict__ shg,
                            const float* __restrict__ shu, const float* __restrict__ shd,
                            u16* __restrict__ wbf) {
  long i0 = (long)blockIdx.x * blockDim.x + threadIdx.x;
  if (i0 < H_ * E_) {
    int k = (int)(i0 >> 5), e = (int)(i0 & 31);
    gwT[i0] = gw[(long)e * H_ + k];
  }
  if (i0 < PADCAP) { tok_list[i0] = 0; wt_list[i0] = 0.f; }
  if (i0 < E_) { counts[i0] = 0; cursor[i0] = 0; }
  if (i0 < 2) qheads[i0] = 0;

  long stride = (long)gridDim.x * blockDim.x;
  for (long i = i0; i < W4_TOT; i += stride) {
    const float* s; long off; long dofs;
    if (i < W4_WG)       { s = wg;  off = i;            dofs = off * 4; }
    else if (i < W4_WU)  { s = wu;  off = i - W4_WG;    dofs = OFF_BU + off * 4; }
    else if (i < W4_WD)  { s = wd;  off = i - W4_WU;    dofs = OFF_BD + off * 4; }
    else if (i < W4_SHG) { s = shg; off = i - W4_WD;    dofs = OFF_BSHG + off * 4; }
    else if (i < W4_SHU) { s = shu; off = i - W4_SHG;   dofs = OFF_BSHU + off * 4; }
    else                 { s = shd; off = i - W4_SHU;   dofs = OFF_BSHD + off * 4; }
    float4 v = ((const float4*)s)[off];
    ushort4 o;
    o.x = f2bf(v.x); o.y = f2bf(v.y); o.z = f2bf(v.z); o.w = f2bf(v.w);
    *(ushort4*)(wbf + dofs) = o;
  }
}

// ---------------- router: logits (f32 exact) + hs->bf16 + fused top-k -------
__global__ __launch_bounds__(256) void router_kernel(
    const float* __restrict__ h, const float* __restrict__ gwT,
    const float* __restrict__ gb, u16* __restrict__ hbf,
    int* __restrict__ idx8, float* __restrict__ wt8, int* __restrict__ counts) {
  __shared__ float sh[8][H_];
  __shared__ float s_log[8][E_ + 1];
  const int tid = threadIdx.x;
  const int t0 = blockIdx.x * 8;
  #pragma unroll
  for (int c = tid; c < 8 * H_ / 4; c += 256) {
    int row = c / (H_ / 4), col = c % (H_ / 4);
    float4 v = ((const float4*)(h + (size_t)(t0 + row) * H_))[col];
    ((float4*)sh[row])[col] = v;
    ushort4 o;
    o.x = f2bf(v.x); o.y = f2bf(v.y); o.z = f2bf(v.z); o.w = f2bf(v.w);
    ((ushort4*)(hbf + (size_t)(t0 + row) * H_))[col] = o;
  }
  __syncthreads();
  {
    const int w = tid >> 6, l = tid & 63;
    const int e = l & 31, tl = w * 2 + (l >> 5);
    const float* hp = sh[tl];
    const float* wp = gwT + e;
    float acc = 0.f;
    #pragma unroll 8
    for (int k = 0; k < H_; ++k) acc += hp[k] * wp[(size_t)k * E_];
    s_log[tl][e] = acc;
  }
  __syncthreads();
  if (tid < 8) {
    const int t = t0 + tid;
    float scr[E_], sc[E_];
    #pragma unroll
    for (int e = 0; e < E_; ++e) {
      float sig = 1.f / (1.f + __expf(-s_log[tid][e]));
      scr[e] = sig;
      sc[e] = sig + gb[e];
    }
    float gs[G_];
    #pragma unroll
    for (int g = 0; g < G_; ++g) {
      float a = sc[g * 4], b = sc[g * 4 + 1], c = sc[g * 4 + 2], d = sc[g * 4 + 3];
      float hi1 = fmaxf(a, b), lo1 = fminf(a, b);
      float hi2 = fmaxf(c, d), lo2 = fminf(c, d);
      float m1 = fmaxf(hi1, hi2);
      float m2 = (hi1 >= hi2) ? fmaxf(lo1, hi2) : fmaxf(lo2, hi1);
      gs[g] = m1 + m2;
    }
    unsigned gm = 0;
    #pragma unroll
    for (int r = 0; r < 4; ++r) {
      float bv = -1e30f; int bi = 0;
      #pragma unroll
      for (int g = 0; g < G_; ++g)
        if (!(gm & (1u << g)) && gs[g] > bv) { bv = gs[g]; bi = g; }
      gm |= 1u << bi;
    }
    float msk[E_];
    #pragma unroll
    for (int e = 0; e < E_; ++e)
      msk[e] = ((gm >> (e >> 2)) & 1u) ? sc[e] : 0.f;
    unsigned um = 0; float wsum = 0.f;
    int idxs[8]; float wts[8];
    #pragma unroll
    for (int r = 0; r < 8; ++r) {
      float bv = -1e30f; int bi = 0;
      #pragma unroll
      for (int e = 0; e < E_; ++e)
        if (!(um & (1u << e)) && msk[e] > bv) { bv = msk[e]; bi = e; }
      um |= 1u << bi;
      idxs[r] = bi;
      float wv = scr[bi];
      wts[r] = wv; wsum += wv;
    }
    float inv = SCALE_ / (wsum + 1e-20f);
    #pragma unroll
    for (int r = 0; r < 8; ++r) {
      idx8[(size_t)t * 8 + r] = idxs[r];
      wt8[(size_t)t * 8 + r] = wts[r] * inv;
      atomicAdd(&counts[idxs[r]], 1);
    }
  }
}

// ---------------- fill (inline padded scan) ----------------
__global__ void fill_kernel(const int* __restrict__ idx8, const float* __restrict__ wt8,
                            const int* __restrict__ counts, int* __restrict__ cursor,
                            int* __restrict__ tok_list, float* __restrict__ wt_list,
                            int* __restrict__ pair_pos, int npair) {
  int i = blockIdx.x * blockDim.x + threadIdx.x;
  if (i >= npair) return;
  int e = idx8[i];
  int offz = 0;
  for (int k = 0; k < E_; ++k) {
    if (k == e) break;
    offz += ((counts[k] + 127) >> 7) << 7;
  }
  int p = atomicAdd(&cursor[e], 1);
  int slot = offz + p;
  tok_list[slot] = i >> 3;
  wt_list[slot] = wt8[i];
  pair_pos[i] = slot;
}

// ---------------- phase 1: persistent dual GEMM, 128x128, BK=32 dbuf --------
// 512 blocks x 256 thr. LDS 48KB (2 blk/CU). One barrier per K-step; prefetch
// of step s+1 issued before compute(s) -> load latency hidden under compute.
// Swizzle (rows are 64B = 4 x 16B blocks): stage block cb^((row>>1)&3),
// read block lh^((lr>>1)&3) -> even 8 accesses/bank (b128 baseline).
__global__ __launch_bounds__(256, 2) void p1_kernel(
    const u16* __restrict__ hbf,
    const u16* __restrict__ wbf,
    const int* __restrict__ counts,
    const int* __restrict__ tok_list, const float* __restrict__ wt_list,
    int* __restrict__ qheads,
    u16* __restrict__ gu,          // [PADCAP][512]
    u16* __restrict__ gu_sh,       // [T][1024]
    int T) {
  __shared__ u16 lsA[2][128 * 32];
  __shared__ u16 lsB0[2][128 * 32];
  __shared__ u16 lsB1[2][128 * 32];
  __shared__ int s_tok[128];
  __shared__ float s_wt[128];
  __shared__ int s_off[E_], s_ntt[E_];
  __shared__ int s_tot, s_tile;

  const int tid = threadIdx.x;
  if (tid == 0) {
    int run = 0, tot = 0;
    for (int e = 0; e < E_; ++e) {
      s_off[e] = run;
      int nt = (counts[e] + 127) >> 7;
      s_ntt[e] = nt;
      run += nt << 7;
      tot += nt * 4;
    }
    s_tot = tot + (T / 128) * 8;
  }

  const int w = tid >> 6, l = tid & 63;
  const int wr = w >> 1, wc = w & 1;
  const int lr = l & 15, lh = l >> 4;
  const int rdblk = (lh ^ ((lr >> 1) & 3)) << 3;   // u16 elems

  // staging geometry: 512 chunks of 16B per buffer, 2 per thread
  const int c0 = tid, c1 = tid + 256;
  const int row0 = c0 >> 2, cb0 = c0 & 3, scb0 = cb0 ^ ((row0 >> 1) & 3);
  const int row1 = c1 >> 2, cb1 = c1 & 3, scb1 = cb1 ^ ((row1 >> 1) & 3);

  for (;;) {
    __syncthreads();
    if (tid == 0) s_tile = atomicAdd(&qheads[0], 1);
    __syncthreads();
    int q = s_tile;
    if (q >= s_tot) break;

    int z = 0, rem = q;
    for (; z < E_; ++z) { int t = s_ntt[z] * 4; if (rem < t) break; rem -= t; }
    const bool sh_e = (z == E_);
    int tt, nb;
    if (sh_e) { tt = rem >> 3; nb = rem & 7; }
    else      { tt = rem >> 2; nb = rem & 3; }
    const int off = sh_e ? 0 : s_off[z];

    if (tid < 128) {
      if (sh_e) { s_tok[tid] = tt * 128 + tid; s_wt[tid] = 1.0f; }
      else {
        int slot = off + tt * 128 + tid;
        s_tok[tid] = tok_list[slot];
        s_wt[tid] = wt_list[slot];
      }
    }
    __syncthreads();

    const u16* Bg = sh_e ? (wbf + OFF_BSHG + (size_t)(nb * 128) * H_)
                         : (wbf + ((size_t)z * I_ + nb * 128) * H_);
    const u16* Bu = sh_e ? (wbf + OFF_BSHU + (size_t)(nb * 128) * H_)
                         : (wbf + OFF_BU + ((size_t)z * I_ + nb * 128) * H_);
    const u16* A0 = hbf + (size_t)s_tok[row0] * H_ + scb0 * 8;
    const u16* A1 = hbf + (size_t)s_tok[row1] * H_ + scb1 * 8;

    f32x4_t acc0[4][4], acc1[4][4];
    #pragma unroll
    for (int m = 0; m < 4; ++m)
      #pragma unroll
      for (int n = 0; n < 4; ++n) {
        acc0[m][n] = (f32x4_t){0.f, 0.f, 0.f, 0.f};
        acc1[m][n] = (f32x4_t){0.f, 0.f, 0.f, 0.f};
      }

    auto stage = [&](int b, int k0) {
      load_lds16(A0 + k0, (char*)&lsA[b][0] + c0 * 16);
      load_lds16(A1 + k0, (char*)&lsA[b][0] + c1 * 16);
      load_lds16(Bg + (size_t)row0 * H_ + k0 + scb0 * 8, (char*)&lsB0[b][0] + c0 * 16);
      load_lds16(Bg + (size_t)row1 * H_ + k0 + scb1 * 8, (char*)&lsB0[b][0] + c1 * 16);
      load_lds16(Bu + (size_t)row0 * H_ + k0 + scb0 * 8, (char*)&lsB1[b][0] + c0 * 16);
      load_lds16(Bu + (size_t)row1 * H_ + k0 + scb1 * 8, (char*)&lsB1[b][0] + c1 * 16);
    };
    auto compute = [&](int b) {
      bf16x8_t af[4], b0f[4], b1f[4];
      #pragma unroll
      for (int m = 0; m < 4; ++m)
        af[m] = *(const bf16x8_t*)(&lsA[b][0] + (wr * 64 + m * 16 + lr) * 32 + rdblk);
      #pragma unroll
      for (int n = 0; n < 4; ++n) {
        b0f[n] = *(const bf16x8_t*)(&lsB0[b][0] + (wc * 64 + n * 16 + lr) * 32 + rdblk);
        b1f[n] = *(const bf16x8_t*)(&lsB1[b][0] + (wc * 64 + n * 16 + lr) * 32 + rdblk);
      }
      #pragma unroll
      for (int m = 0; m < 4; ++m)
        #pragma unroll
        for (int n = 0; n < 4; ++n) {
          acc0[m][n] = __builtin_amdgcn_mfma_f32_16x16x32_bf16(af[m], b0f[n], acc0[m][n], 0, 0, 0);
          acc1[m][n] = __builtin_amdgcn_mfma_f32_16x16x32_bf16(af[m], b1f[n], acc1[m][n], 0, 0, 0);
        }
    };

    stage(0, 0);
    __syncthreads();
    int cur = 0;
    #pragma unroll 1
    for (int s = 0; s < 32; ++s) {
      if (s < 31) stage(cur ^ 1, (s + 1) * 32);
      compute(cur);
      __syncthreads();
      cur ^= 1;
    }

    const int ldo = sh_e ? (I_ * NSH_) : I_;
    u16* outp = sh_e ? (gu_sh + (size_t)(tt * 128) * ldo + nb * 128)
                     : (gu + (size_t)(off + tt * 128) * ldo + nb * 128);
    #pragma unroll
    for (int m = 0; m < 4; ++m) {
      #pragma unroll
      for (int n = 0; n < 4; ++n) {
        int col = wc * 64 + n * 16 + lr;
        #pragma unroll
        for (int j = 0; j < 4; ++j) {
          int trow = wr * 64 + m * 16 + lh * 4 + j;
          float gv = acc0[m][n][j], uv = acc1[m][n][j];
          float sv = gv / (1.f + __expf(-gv));
          outp[(size_t)trow * ldo + col] = f2bf(sv * uv * s_wt[trow]);
        }
      }
    }
  }
}

// ---------------- phase 2: persistent GEMM (down), 128x128, BK=32 dbuf ------
// 768 blocks x 256 thr. LDS 32KB (3+ blk/CU).
__global__ __launch_bounds__(256, 3) void p2_kernel(
    const u16* __restrict__ gu, const u16* __restrict__ gu_sh,
    const u16* __restrict__ wbf,
    const int* __restrict__ counts,
    int* __restrict__ qheads,
    u16* __restrict__ part,        // [PADCAP][H]
    u16* __restrict__ part_sh,     // [T][H]
    int T) {
  __shared__ u16 lsA[2][128 * 32];
  __shared__ u16 lsB[2][128 * 32];
  __shared__ int s_off[E_], s_ntt[E_];
  __shared__ int s_tot, s_tile;

  const int tid = threadIdx.x;
  if (tid == 0) {
    int run = 0, tot = 0;
    for (int e = 0; e < E_; ++e) {
      s_off[e] = run;
      int nt = (counts[e] + 127) >> 7;
      s_ntt[e] = nt;
      run += nt << 7;
      tot += nt * 8;
    }
    s_tot = tot + (T / 128) * 8;
  }

  const int w = tid >> 6, l = tid & 63;
  const int wr = w >> 1, wc = w & 1;
  const int lr = l & 15, lh = l >> 4;
  const int rdblk = (lh ^ ((lr >> 1) & 3)) << 3;

  const int c0 = tid, c1 = tid + 256;
  const int row0 = c0 >> 2, cb0 = c0 & 3, scb0 = cb0 ^ ((row0 >> 1) & 3);
  const int row1 = c1 >> 2, cb1 = c1 & 3, scb1 = cb1 ^ ((row1 >> 1) & 3);

  for (;;) {
    __syncthreads();
    if (tid == 0) s_tile = atomicAdd(&qheads[1], 1);
    __syncthreads();
    int q = s_tile;
    if (q >= s_tot) break;

    int z = 0, rem = q;
    for (; z < E_; ++z) { int t = s_ntt[z] * 8; if (rem < t) break; rem -= t; }
    const bool sh_e = (z == E_);
    int tt = rem >> 3, nb = rem & 7;

    const int K = sh_e ? (I_ * NSH_) : I_;
    const int NT = K / 32;
    const u16* Ab = sh_e ? (gu_sh + (size_t)(tt * 128) * K)
                         : (gu + (size_t)(s_off[z] + tt * 128) * K);
    const u16* Bb = sh_e ? (wbf + OFF_BSHD + (size_t)(nb * 128) * K)
                         : (wbf + OFF_BD + (size_t)z * H_ * I_ + (size_t)(nb * 128) * K);
    u16* outp = sh_e ? (part_sh + (size_t)(tt * 128) * H_ + nb * 128)
                     : (part + (size_t)(s_off[z] + tt * 128) * H_ + nb * 128);

    f32x4_t acc[4][4];
    #pragma unroll
    for (int m = 0; m < 4; ++m)
      #pragma unroll
      for (int n = 0; n < 4; ++n) acc[m][n] = (f32x4_t){0.f, 0.f, 0.f, 0.f};

    auto stage = [&](int b, int k0) {
      load_lds16(Ab + (size_t)row0 * K + k0 + scb0 * 8, (char*)&lsA[b][0] + c0 * 16);
      load_lds16(Ab + (size_t)row1 * K + k0 + scb1 * 8, (char*)&lsA[b][0] + c1 * 16);
      load_lds16(Bb + (size_t)row0 * K + k0 + scb0 * 8, (char*)&lsB[b][0] + c0 * 16);
      load_lds16(Bb + (size_t)row1 * K + k0 + scb1 * 8, (char*)&lsB[b][0] + c1 * 16);
    };
    auto compute = [&](int b) {
      bf16x8_t af[4], bf[4];
      #pragma unroll
      for (int m = 0; m < 4; ++m)
        af[m] = *(const bf16x8_t*)(&lsA[b][0] + (wr * 64 + m * 16 + lr) * 32 + rdblk);
      #pragma unroll
      for (int n = 0; n < 4; ++n)
        bf[n] = *(const bf16x8_t*)(&lsB[b][0] + (wc * 64 + n * 16 + lr) * 32 + rdblk);
      #pragma unroll
      for (int m = 0; m < 4; ++m)
        #pragma unroll
        for (int n = 0; n < 4; ++n)
          acc[m][n] = __builtin_amdgcn_mfma_f32_16x16x32_bf16(af[m], bf[n], acc[m][n], 0, 0, 0);
    };

    stage(0, 0);
    __syncthreads();
    int cur = 0;
    #pragma unroll 1
    for (int s = 0; s < NT; ++s) {
      if (s < NT - 1) stage(cur ^ 1, (s + 1) * 32);
      compute(cur);
      __syncthreads();
      cur ^= 1;
    }

    #pragma unroll
    for (int m = 0; m < 4; ++m) {
      #pragma unroll
      for (int n = 0; n < 4; ++n) {
        int col = wc * 64 + n * 16 + lr;
        #pragma unroll
        for (int j = 0; j < 4; ++j) {
          int trow = wr * 64 + m * 16 + lh * 4 + j;
          outp[(size_t)trow * H_ + col] = f2bf(acc[m][n][j]);
        }
      }
    }
  }
}

// ---------------- combine ----------------
__global__ void combine_kernel(const u16* __restrict__ part, const u16* __restrict__ part_sh,
                               const int* __restrict__ pair_pos, float* __restrict__ out) {
  int t = blockIdx.x;
  int h = threadIdx.x * 4;
  int pp[8];
  #pragma unroll
  for (int s = 0; s < 8; ++s) pp[s] = pair_pos[(long)t * 8 + s];
  ushort4 v = *(const ushort4*)(part_sh + (size_t)t * H_ + h);
  float a0 = bf2f(v.x), a1 = bf2f(v.y), a2 = bf2f(v.z), a3 = bf2f(v.w);
  #pragma unroll
  for (int s = 0; s < 8; ++s) {
    ushort4 u = *(const ushort4*)(part + (size_t)pp[s] * H_ + h);
    a0 += bf2f(u.x); a1 += bf2f(u.y); a2 += bf2f(u.z); a3 += bf2f(u.w);
  }
  float4 o = {a0, a1, a2, a3};
  *(float4*)(out + (size_t)t * H_ + h) = o;
}

extern "C" void kernel_launch(void* const* d_in, const int* in_sizes, int n_in,
                              void* d_out, int out_size, void* d_ws, size_t ws_size,
                              hipStream_t stream) {
  const float* hs  = (const float*)d_in[0];
  const float* gw  = (const float*)d_in[1];
  const float* gb  = (const float*)d_in[2];
  const float* wg  = (const float*)d_in[3];
  const float* wu  = (const float*)d_in[4];
  const float* wd  = (const float*)d_in[5];
  const float* shg = (const float*)d_in[6];
  const float* shu = (const float*)d_in[7];
  const float* shd = (const float*)d_in[8];
  float* out = (float*)d_out;

  const int T = in_sizes[0] / H_;  // 2048

  char* ws = (char*)d_ws;
  size_t off = 0;
  auto alloc = [&](size_t bytes) {
    char* p = ws + off;
    off += (bytes + 255) & ~(size_t)255;
    return p;
  };
  int*   counts   = (int*)alloc(E_ * 4);
  int*   cursor   = (int*)alloc(E_ * 4);
  int*   qheads   = (int*)alloc(2 * 4);
  int*   idx8     = (int*)alloc((size_t)T * 8 * 4);
  float* wt8      = (float*)alloc((size_t)T * 8 * 4);
  int*   pair_pos = (int*)alloc((size_t)T * 8 * 4);
  int*   tok_list = (int*)alloc(PADCAP * 4);
  float* wt_list  = (float*)alloc(PADCAP * 4);
  float* gwT      = (float*)alloc((size_t)H_ * E_ * 4);
  u16* hbf     = (u16*)alloc((size_t)T * H_ * 2);
  u16* wbf     = (u16*)alloc((size_t)WBF_TOT * 2);
  u16* gu      = (u16*)alloc((size_t)PADCAP * I_ * 2);
  u16* gu_sh   = (u16*)alloc((size_t)T * I_ * NSH_ * 2);
  u16* part    = (u16*)alloc((size_t)PADCAP * H_ * 2);
  u16* part_sh = (u16*)alloc((size_t)T * H_ * 2);
  if (off > ws_size) return;

  hipLaunchKernelGGL(prep_kernel, dim3(4096), dim3(256), 0, stream,
                     gw, gwT, counts, cursor, qheads, tok_list, wt_list,
                     wg, wu, wd, shg, shu, shd, wbf);

  hipLaunchKernelGGL(router_kernel, dim3(T / 8), dim3(256), 0, stream,
                     hs, gwT, gb, hbf, idx8, wt8, counts);

  hipLaunchKernelGGL(fill_kernel, dim3((T * 8 + 255) / 256), dim3(256), 0, stream,
                     idx8, wt8, counts, cursor, tok_list, wt_list, pair_pos, T * 8);

  hipLaunchKernelGGL(p1_kernel, dim3(512), dim3(256), 0, stream,
                     hbf, wbf, counts, tok_list, wt_list, qheads, gu, gu_sh, T);

  hipLaunchKernelGGL(p2_kernel, dim3(768), dim3(256), 0, stream,
                     gu, gu_sh, wbf, counts, qheads, part, part_sh, T);

  hipLaunchKernelGGL(combine_kernel, dim3(T), dim3(256), 0, stream,
                     part, part_sh, pair_pos, out);
}

// Round 11
// 268.497 us; speedup vs baseline: 1.3430x; 1.1515x over previous
//
#include <hip/hip_runtime.h>
#include <hip/hip_bf16.h>
#include <cstdint>

#define E_ 32
#define H_ 1024
#define I_ 512
#define G_ 8
#define NSH_ 2
#define SCALE_ 2.5f
#define NROUTED (E_ * I_)            // 16384
#define PADCAP (16384 + E_ * 128)    // 20480, pad-to-128

typedef unsigned short u16;
using bf16x8_t = __attribute__((ext_vector_type(8))) __bf16;
using f32x4_t  = __attribute__((ext_vector_type(4))) float;

__device__ __forceinline__ u16 f2bf(float x) {
  union { float f; uint32_t u; } v; v.f = x;
  uint32_t u = v.u;
  uint32_t r = (u + 0x7fffu + ((u >> 16) & 1u)) >> 16;
  return (u16)r;
}
__device__ __forceinline__ float bf2f(u16 x) {
  union { uint32_t u; float f; } v; v.u = ((uint32_t)x) << 16; return v.f;
}

__device__ __forceinline__ void load_lds16(const void* g, void* l) {
  __builtin_amdgcn_global_load_lds(
      (const __attribute__((address_space(1))) unsigned int*)g,
      (__attribute__((address_space(3))) unsigned int*)l,
      16, 0, 0);
}

// u16-element offsets inside wbf: [bg | bu | bd | bshg | bshu | bshd]
#define OFF_BU   16777216L
#define OFF_BD   33554432L
#define OFF_BSHG 50331648L
#define OFF_BSHU 51380224L
#define OFF_BSHD 52428800L
#define WBF_TOT  53477376L

// ---------------- prep: init + gw transpose + all-weight f32->bf16 ----------
#define W4_WG  4194304L
#define W4_WU  8388608L
#define W4_WD  12582912L
#define W4_SHG 12845056L
#define W4_SHU 13107200L
#define W4_TOT 13369344L
__global__ void prep_kernel(const float* __restrict__ gw, float* __restrict__ gwT,
                            int* __restrict__ counts, int* __restrict__ cursor,
                            int* __restrict__ qheads,
                            int* __restrict__ tok_list, float* __restrict__ wt_list,
                            const float* __restrict__ wg, const float* __restrict__ wu,
                            const float* __restrict__ wd, const float* __restrict__ shg,
                            const float* __restrict__ shu, const float* __restrict__ shd,
                            u16* __restrict__ wbf) {
  long i0 = (long)blockIdx.x * blockDim.x + threadIdx.x;
  if (i0 < H_ * E_) {
    int k = (int)(i0 >> 5), e = (int)(i0 & 31);
    gwT[i0] = gw[(long)e * H_ + k];
  }
  if (i0 < PADCAP) { tok_list[i0] = 0; wt_list[i0] = 0.f; }
  if (i0 < E_) { counts[i0] = 0; cursor[i0] = 0; }
  if (i0 < 2) qheads[i0] = 0;

  long stride = (long)gridDim.x * blockDim.x;
  for (long i = i0; i < W4_TOT; i += stride) {
    const float* s; long off; long dofs;
    if (i < W4_WG)       { s = wg;  off = i;            dofs = off * 4; }
    else if (i < W4_WU)  { s = wu;  off = i - W4_WG;    dofs = OFF_BU + off * 4; }
    else if (i < W4_WD)  { s = wd;  off = i - W4_WU;    dofs = OFF_BD + off * 4; }
    else if (i < W4_SHG) { s = shg; off = i - W4_WD;    dofs = OFF_BSHG + off * 4; }
    else if (i < W4_SHU) { s = shu; off = i - W4_SHG;   dofs = OFF_BSHU + off * 4; }
    else                 { s = shd; off = i - W4_SHU;   dofs = OFF_BSHD + off * 4; }
    float4 v = ((const float4*)s)[off];
    ushort4 o;
    o.x = f2bf(v.x); o.y = f2bf(v.y); o.z = f2bf(v.z); o.w = f2bf(v.w);
    *(ushort4*)(wbf + dofs) = o;
  }
}

// ---------------- logits: split-K partials + hs->bf16 -----------------------
// grid (T/64, 8). LDS: h slice [64][128] f32 (32KB) + gwT slice [128][32] (16KB).
// Each thread: expert e = tid&31, 8 tokens -> 8 independent acc chains (ILP).
__global__ __launch_bounds__(256) void logits_kernel(
    const float* __restrict__ h, const float* __restrict__ gwT,
    float* __restrict__ lpart,   // [8][T][E]
    u16* __restrict__ hbf, int T) {
  __shared__ float shh[64][128];
  __shared__ float shw[128][E_];
  const int tid = threadIdx.x;
  const int t0 = blockIdx.x * 64;
  const int k0 = blockIdx.y * 128;
  #pragma unroll
  for (int i = 0; i < 8; ++i) {
    int c = tid + 256 * i;            // 2048 float4 chunks
    int row = c >> 5, col = c & 31;
    float4 v = *(const float4*)(h + (size_t)(t0 + row) * H_ + k0 + col * 4);
    *(float4*)(&shh[row][col * 4]) = v;
    ushort4 o;
    o.x = f2bf(v.x); o.y = f2bf(v.y); o.z = f2bf(v.z); o.w = f2bf(v.w);
    *(ushort4*)(hbf + (size_t)(t0 + row) * H_ + k0 + col * 4) = o;
  }
  #pragma unroll
  for (int i = 0; i < 4; ++i) {
    int c = tid + 256 * i;            // 1024 float4 chunks
    int row = c >> 3, col = c & 7;
    *(float4*)(&shw[row][col * 4]) =
        *(const float4*)(gwT + (size_t)(k0 + row) * E_ + col * 4);
  }
  __syncthreads();
  const int e = tid & 31;
  const int tb = (tid >> 5) * 8;
  float acc[8] = {0.f, 0.f, 0.f, 0.f, 0.f, 0.f, 0.f, 0.f};
  #pragma unroll 4
  for (int k = 0; k < 128; ++k) {
    float wv = shw[k][e];
    #pragma unroll
    for (int j = 0; j < 8; ++j) acc[j] += shh[tb + j][k] * wv;
  }
  #pragma unroll
  for (int j = 0; j < 8; ++j)
    lpart[((size_t)blockIdx.y * T + (t0 + tb + j)) * E_ + e] = acc[j];
}

// ---------------- topk: wave-parallel (lane=expert, half-wave=token) --------
// block 256 = 4 waves; wave = 2 tokens; grid T/8.
__global__ __launch_bounds__(256) void topk_kernel(
    const float* __restrict__ lpart, const float* __restrict__ gb,
    int* __restrict__ idx8, float* __restrict__ wt8, int* __restrict__ counts,
    int T) {
  const int tid = threadIdx.x;
  const int l = tid & 63, wid = tid >> 6;
  const int e = l & 31, half = l >> 5;
  const int t = blockIdx.x * 8 + wid * 2 + half;

  float lg = 0.f;
  #pragma unroll
  for (int s = 0; s < 8; ++s) lg += lpart[((size_t)s * T + t) * E_ + e];
  float score = 1.f / (1.f + __expf(-lg));
  float sc = score + gb[e];

  // group score: sum of top-2 within each group of 4 experts
  float x1 = __shfl_xor(sc, 1);
  float x2 = __shfl_xor(sc, 2);
  float x3 = __shfl_xor(sc, 3);
  float hi1 = fmaxf(sc, x1), lo1 = fminf(sc, x1);
  float hi2 = fmaxf(x2, x3), lo2 = fminf(x2, x3);
  float m1 = fmaxf(hi1, hi2);
  float m2 = (hi1 >= hi2) ? fmaxf(lo1, hi2) : fmaxf(lo2, hi1);
  float gs = m1 + m2;     // uniform within group of 4 lanes

  // gather the 8 group scores (per half-wave) and pick top-4 groups
  float ga[8];
  #pragma unroll
  for (int g = 0; g < 8; ++g) ga[g] = __shfl(gs, (half << 5) + g * 4);
  unsigned gm = 0;
  #pragma unroll
  for (int r = 0; r < 4; ++r) {
    float bv = -1e30f; int bi = 0;
    #pragma unroll
    for (int g = 0; g < 8; ++g)
      if (!((gm >> g) & 1u) && ga[g] > bv) { bv = ga[g]; bi = g; }
    gm |= 1u << bi;
  }
  float msk = ((gm >> (e >> 2)) & 1u) ? sc : 0.f;

  // iterative top-8 argmax via butterfly (lowest index wins ties)
  float wsum = 0.f, myw = 0.f;
  int myi = 0;
  #pragma unroll
  for (int r = 0; r < 8; ++r) {
    float av = msk; int ai = e;
    #pragma unroll
    for (int m = 16; m; m >>= 1) {
      float ov = __shfl_xor(av, m);
      int oi = __shfl_xor(ai, m);
      if (ov > av || (ov == av && oi < ai)) { av = ov; ai = oi; }
    }
    float wscore = __shfl(score, (half << 5) + ai);
    wsum += wscore;
    if (e == r) { myi = ai; myw = wscore; }
    if (e == ai) msk = 0.f;
  }
  float inv = SCALE_ / (wsum + 1e-20f);
  if (e < 8) {
    idx8[(size_t)t * 8 + e] = myi;
    wt8[(size_t)t * 8 + e] = myw * inv;
    atomicAdd(&counts[myi], 1);
  }
}

// ---------------- fill (inline padded scan) ----------------
__global__ void fill_kernel(const int* __restrict__ idx8, const float* __restrict__ wt8,
                            const int* __restrict__ counts, int* __restrict__ cursor,
                            int* __restrict__ tok_list, float* __restrict__ wt_list,
                            int* __restrict__ pair_pos, int npair) {
  int i = blockIdx.x * blockDim.x + threadIdx.x;
  if (i >= npair) return;
  int e = idx8[i];
  int offz = 0;
  for (int k = 0; k < E_; ++k) {
    if (k == e) break;
    offz += ((counts[k] + 127) >> 7) << 7;
  }
  int p = atomicAdd(&cursor[e], 1);
  int slot = offz + p;
  tok_list[slot] = i >> 3;
  wt_list[slot] = wt8[i];
  pair_pos[i] = slot;
}

// ---------------- phase 1: persistent dual GEMM, 128x128, BK=32 dbuf --------
__global__ __launch_bounds__(256, 2) void p1_kernel(
    const u16* __restrict__ hbf,
    const u16* __restrict__ wbf,
    const int* __restrict__ counts,
    const int* __restrict__ tok_list, const float* __restrict__ wt_list,
    int* __restrict__ qheads,
    u16* __restrict__ gu,          // [PADCAP][512]
    u16* __restrict__ gu_sh,       // [T][1024]
    int T) {
  __shared__ u16 lsA[2][128 * 32];
  __shared__ u16 lsB0[2][128 * 32];
  __shared__ u16 lsB1[2][128 * 32];
  __shared__ int s_tok[128];
  __shared__ float s_wt[128];
  __shared__ int s_off[E_], s_ntt[E_];
  __shared__ int s_tot, s_tile;

  const int tid = threadIdx.x;
  if (tid == 0) {
    int run = 0, tot = 0;
    for (int e = 0; e < E_; ++e) {
      s_off[e] = run;
      int nt = (counts[e] + 127) >> 7;
      s_ntt[e] = nt;
      run += nt << 7;
      tot += nt * 4;
    }
    s_tot = tot + (T / 128) * 8;
  }

  const int w = tid >> 6, l = tid & 63;
  const int wr = w >> 1, wc = w & 1;
  const int lr = l & 15, lh = l >> 4;
  const int rdblk = (lh ^ ((lr >> 1) & 3)) << 3;

  const int c0 = tid, c1 = tid + 256;
  const int row0 = c0 >> 2, cb0 = c0 & 3, scb0 = cb0 ^ ((row0 >> 1) & 3);
  const int row1 = c1 >> 2, cb1 = c1 & 3, scb1 = cb1 ^ ((row1 >> 1) & 3);

  for (;;) {
    __syncthreads();
    if (tid == 0) s_tile = atomicAdd(&qheads[0], 1);
    __syncthreads();
    int q = s_tile;
    if (q >= s_tot) break;

    int z = 0, rem = q;
    for (; z < E_; ++z) { int t = s_ntt[z] * 4; if (rem < t) break; rem -= t; }
    const bool sh_e = (z == E_);
    int tt, nb;
    if (sh_e) { tt = rem >> 3; nb = rem & 7; }
    else      { tt = rem >> 2; nb = rem & 3; }
    const int off = sh_e ? 0 : s_off[z];

    if (tid < 128) {
      if (sh_e) { s_tok[tid] = tt * 128 + tid; s_wt[tid] = 1.0f; }
      else {
        int slot = off + tt * 128 + tid;
        s_tok[tid] = tok_list[slot];
        s_wt[tid] = wt_list[slot];
      }
    }
    __syncthreads();

    const u16* Bg = sh_e ? (wbf + OFF_BSHG + (size_t)(nb * 128) * H_)
                         : (wbf + ((size_t)z * I_ + nb * 128) * H_);
    const u16* Bu = sh_e ? (wbf + OFF_BSHU + (size_t)(nb * 128) * H_)
                         : (wbf + OFF_BU + ((size_t)z * I_ + nb * 128) * H_);
    const u16* A0 = hbf + (size_t)s_tok[row0] * H_ + scb0 * 8;
    const u16* A1 = hbf + (size_t)s_tok[row1] * H_ + scb1 * 8;

    f32x4_t acc0[4][4], acc1[4][4];
    #pragma unroll
    for (int m = 0; m < 4; ++m)
      #pragma unroll
      for (int n = 0; n < 4; ++n) {
        acc0[m][n] = (f32x4_t){0.f, 0.f, 0.f, 0.f};
        acc1[m][n] = (f32x4_t){0.f, 0.f, 0.f, 0.f};
      }

    auto stage = [&](int b, int k0) {
      load_lds16(A0 + k0, (char*)&lsA[b][0] + c0 * 16);
      load_lds16(A1 + k0, (char*)&lsA[b][0] + c1 * 16);
      load_lds16(Bg + (size_t)row0 * H_ + k0 + scb0 * 8, (char*)&lsB0[b][0] + c0 * 16);
      load_lds16(Bg + (size_t)row1 * H_ + k0 + scb1 * 8, (char*)&lsB0[b][0] + c1 * 16);
      load_lds16(Bu + (size_t)row0 * H_ + k0 + scb0 * 8, (char*)&lsB1[b][0] + c0 * 16);
      load_lds16(Bu + (size_t)row1 * H_ + k0 + scb1 * 8, (char*)&lsB1[b][0] + c1 * 16);
    };
    auto compute = [&](int b) {
      bf16x8_t af[4], b0f[4], b1f[4];
      #pragma unroll
      for (int m = 0; m < 4; ++m)
        af[m] = *(const bf16x8_t*)(&lsA[b][0] + (wr * 64 + m * 16 + lr) * 32 + rdblk);
      #pragma unroll
      for (int n = 0; n < 4; ++n) {
        b0f[n] = *(const bf16x8_t*)(&lsB0[b][0] + (wc * 64 + n * 16 + lr) * 32 + rdblk);
        b1f[n] = *(const bf16x8_t*)(&lsB1[b][0] + (wc * 64 + n * 16 + lr) * 32 + rdblk);
      }
      #pragma unroll
      for (int m = 0; m < 4; ++m)
        #pragma unroll
        for (int n = 0; n < 4; ++n) {
          acc0[m][n] = __builtin_amdgcn_mfma_f32_16x16x32_bf16(af[m], b0f[n], acc0[m][n], 0, 0, 0);
          acc1[m][n] = __builtin_amdgcn_mfma_f32_16x16x32_bf16(af[m], b1f[n], acc1[m][n], 0, 0, 0);
        }
    };

    stage(0, 0);
    __syncthreads();
    int cur = 0;
    #pragma unroll 1
    for (int s = 0; s < 32; ++s) {
      if (s < 31) stage(cur ^ 1, (s + 1) * 32);
      compute(cur);
      __syncthreads();
      cur ^= 1;
    }

    const int ldo = sh_e ? (I_ * NSH_) : I_;
    u16* outp = sh_e ? (gu_sh + (size_t)(tt * 128) * ldo + nb * 128)
                     : (gu + (size_t)(off + tt * 128) * ldo + nb * 128);
    #pragma unroll
    for (int m = 0; m < 4; ++m) {
      #pragma unroll
      for (int n = 0; n < 4; ++n) {
        int col = wc * 64 + n * 16 + lr;
        #pragma unroll
        for (int j = 0; j < 4; ++j) {
          int trow = wr * 64 + m * 16 + lh * 4 + j;
          float gv = acc0[m][n][j], uv = acc1[m][n][j];
          float sv = gv / (1.f + __expf(-gv));
          outp[(size_t)trow * ldo + col] = f2bf(sv * uv * s_wt[trow]);
        }
      }
    }
  }
}

// ---------------- phase 2: persistent GEMM (down), 128x128, BK=32 dbuf ------
__global__ __launch_bounds__(256, 3) void p2_kernel(
    const u16* __restrict__ gu, const u16* __restrict__ gu_sh,
    const u16* __restrict__ wbf,
    const int* __restrict__ counts,
    int* __restrict__ qheads,
    u16* __restrict__ part,        // [PADCAP][H]
    u16* __restrict__ part_sh,     // [T][H]
    int T) {
  __shared__ u16 lsA[2][128 * 32];
  __shared__ u16 lsB[2][128 * 32];
  __shared__ int s_off[E_], s_ntt[E_];
  __shared__ int s_tot, s_tile;

  const int tid = threadIdx.x;
  if (tid == 0) {
    int run = 0, tot = 0;
    for (int e = 0; e < E_; ++e) {
      s_off[e] = run;
      int nt = (counts[e] + 127) >> 7;
      s_ntt[e] = nt;
      run += nt << 7;
      tot += nt * 8;
    }
    s_tot = tot + (T / 128) * 8;
  }

  const int w = tid >> 6, l = tid & 63;
  const int wr = w >> 1, wc = w & 1;
  const int lr = l & 15, lh = l >> 4;
  const int rdblk = (lh ^ ((lr >> 1) & 3)) << 3;

  const int c0 = tid, c1 = tid + 256;
  const int row0 = c0 >> 2, cb0 = c0 & 3, scb0 = cb0 ^ ((row0 >> 1) & 3);
  const int row1 = c1 >> 2, cb1 = c1 & 3, scb1 = cb1 ^ ((row1 >> 1) & 3);

  for (;;) {
    __syncthreads();
    if (tid == 0) s_tile = atomicAdd(&qheads[1], 1);
    __syncthreads();
    int q = s_tile;
    if (q >= s_tot) break;

    int z = 0, rem = q;
    for (; z < E_; ++z) { int t = s_ntt[z] * 8; if (rem < t) break; rem -= t; }
    const bool sh_e = (z == E_);
    int tt = rem >> 3, nb = rem & 7;

    const int K = sh_e ? (I_ * NSH_) : I_;
    const int NT = K / 32;
    const u16* Ab = sh_e ? (gu_sh + (size_t)(tt * 128) * K)
                         : (gu + (size_t)(s_off[z] + tt * 128) * K);
    const u16* Bb = sh_e ? (wbf + OFF_BSHD + (size_t)(nb * 128) * K)
                         : (wbf + OFF_BD + (size_t)z * H_ * I_ + (size_t)(nb * 128) * K);
    u16* outp = sh_e ? (part_sh + (size_t)(tt * 128) * H_ + nb * 128)
                     : (part + (size_t)(s_off[z] + tt * 128) * H_ + nb * 128);

    f32x4_t acc[4][4];
    #pragma unroll
    for (int m = 0; m < 4; ++m)
      #pragma unroll
      for (int n = 0; n < 4; ++n) acc[m][n] = (f32x4_t){0.f, 0.f, 0.f, 0.f};

    auto stage = [&](int b, int k0) {
      load_lds16(Ab + (size_t)row0 * K + k0 + scb0 * 8, (char*)&lsA[b][0] + c0 * 16);
      load_lds16(Ab + (size_t)row1 * K + k0 + scb1 * 8, (char*)&lsA[b][0] + c1 * 16);
      load_lds16(Bb + (size_t)row0 * K + k0 + scb0 * 8, (char*)&lsB[b][0] + c0 * 16);
      load_lds16(Bb + (size_t)row1 * K + k0 + scb1 * 8, (char*)&lsB[b][0] + c1 * 16);
    };
    auto compute = [&](int b) {
      bf16x8_t af[4], bf[4];
      #pragma unroll
      for (int m = 0; m < 4; ++m)
        af[m] = *(const bf16x8_t*)(&lsA[b][0] + (wr * 64 + m * 16 + lr) * 32 + rdblk);
      #pragma unroll
      for (int n = 0; n < 4; ++n)
        bf[n] = *(const bf16x8_t*)(&lsB[b][0] + (wc * 64 + n * 16 + lr) * 32 + rdblk);
      #pragma unroll
      for (int m = 0; m < 4; ++m)
        #pragma unroll
        for (int n = 0; n < 4; ++n)
          acc[m][n] = __builtin_amdgcn_mfma_f32_16x16x32_bf16(af[m], bf[n], acc[m][n], 0, 0, 0);
    };

    stage(0, 0);
    __syncthreads();
    int cur = 0;
    #pragma unroll 1
    for (int s = 0; s < NT; ++s) {
      if (s < NT - 1) stage(cur ^ 1, (s + 1) * 32);
      compute(cur);
      __syncthreads();
      cur ^= 1;
    }

    #pragma unroll
    for (int m = 0; m < 4; ++m) {
      #pragma unroll
      for (int n = 0; n < 4; ++n) {
        int col = wc * 64 + n * 16 + lr;
        #pragma unroll
        for (int j = 0; j < 4; ++j) {
          int trow = wr * 64 + m * 16 + lh * 4 + j;
          outp[(size_t)trow * H_ + col] = f2bf(acc[m][n][j]);
        }
      }
    }
  }
}

// ---------------- combine ----------------
__global__ void combine_kernel(const u16* __restrict__ part, const u16* __restrict__ part_sh,
                               const int* __restrict__ pair_pos, float* __restrict__ out) {
  int t = blockIdx.x;
  int h = threadIdx.x * 4;
  int pp[8];
  #pragma unroll
  for (int s = 0; s < 8; ++s) pp[s] = pair_pos[(long)t * 8 + s];
  ushort4 v = *(const ushort4*)(part_sh + (size_t)t * H_ + h);
  float a0 = bf2f(v.x), a1 = bf2f(v.y), a2 = bf2f(v.z), a3 = bf2f(v.w);
  #pragma unroll
  for (int s = 0; s < 8; ++s) {
    ushort4 u = *(const ushort4*)(part + (size_t)pp[s] * H_ + h);
    a0 += bf2f(u.x); a1 += bf2f(u.y); a2 += bf2f(u.z); a3 += bf2f(u.w);
  }
  float4 o = {a0, a1, a2, a3};
  *(float4*)(out + (size_t)t * H_ + h) = o;
}

extern "C" void kernel_launch(void* const* d_in, const int* in_sizes, int n_in,
                              void* d_out, int out_size, void* d_ws, size_t ws_size,
                              hipStream_t stream) {
  const float* hs  = (const float*)d_in[0];
  const float* gw  = (const float*)d_in[1];
  const float* gb  = (const float*)d_in[2];
  const float* wg  = (const float*)d_in[3];
  const float* wu  = (const float*)d_in[4];
  const float* wd  = (const float*)d_in[5];
  const float* shg = (const float*)d_in[6];
  const float* shu = (const float*)d_in[7];
  const float* shd = (const float*)d_in[8];
  float* out = (float*)d_out;

  const int T = in_sizes[0] / H_;  // 2048

  char* ws = (char*)d_ws;
  size_t off = 0;
  auto alloc = [&](size_t bytes) {
    char* p = ws + off;
    off += (bytes + 255) & ~(size_t)255;
    return p;
  };
  int*   counts   = (int*)alloc(E_ * 4);
  int*   cursor   = (int*)alloc(E_ * 4);
  int*   qheads   = (int*)alloc(2 * 4);
  int*   idx8     = (int*)alloc((size_t)T * 8 * 4);
  float* wt8      = (float*)alloc((size_t)T * 8 * 4);
  int*   pair_pos = (int*)alloc((size_t)T * 8 * 4);
  int*   tok_list = (int*)alloc(PADCAP * 4);
  float* wt_list  = (float*)alloc(PADCAP * 4);
  float* gwT      = (float*)alloc((size_t)H_ * E_ * 4);
  float* lpart    = (float*)alloc((size_t)8 * T * E_ * 4);
  u16* hbf     = (u16*)alloc((size_t)T * H_ * 2);
  u16* wbf     = (u16*)alloc((size_t)WBF_TOT * 2);
  u16* gu      = (u16*)alloc((size_t)PADCAP * I_ * 2);
  u16* gu_sh   = (u16*)alloc((size_t)T * I_ * NSH_ * 2);
  u16* part    = (u16*)alloc((size_t)PADCAP * H_ * 2);
  u16* part_sh = (u16*)alloc((size_t)T * H_ * 2);
  if (off > ws_size) return;

  hipLaunchKernelGGL(prep_kernel, dim3(4096), dim3(256), 0, stream,
                     gw, gwT, counts, cursor, qheads, tok_list, wt_list,
                     wg, wu, wd, shg, shu, shd, wbf);

  hipLaunchKernelGGL(logits_kernel, dim3(T / 64, 8), dim3(256), 0, stream,
                     hs, gwT, lpart, hbf, T);

  hipLaunchKernelGGL(topk_kernel, dim3(T / 8), dim3(256), 0, stream,
                     lpart, gb, idx8, wt8, counts, T);

  hipLaunchKernelGGL(fill_kernel, dim3((T * 8 + 255) / 256), dim3(256), 0, stream,
                     idx8, wt8, counts, cursor, tok_list, wt_list, pair_pos, T * 8);

  hipLaunchKernelGGL(p1_kernel, dim3(512), dim3(256), 0, stream,
                     hbf, wbf, counts, tok_list, wt_list, qheads, gu, gu_sh, T);

  hipLaunchKernelGGL(p2_kernel, dim3(768), dim3(256), 0, stream,
                     gu, gu_sh, wbf, counts, qheads, part, part_sh, T);

  hipLaunchKernelGGL(combine_kernel, dim3(T), dim3(256), 0, stream,
                     part, part_sh, pair_pos, out);
}

// Round 12
// 266.445 us; speedup vs baseline: 1.3533x; 1.0077x over previous
//
#include <hip/hip_runtime.h>
#include <hip/hip_bf16.h>
#include <cstdint>

#define E_ 32
#define H_ 1024
#define I_ 512
#define G_ 8
#define NSH_ 2
#define SCALE_ 2.5f
#define NROUTED (E_ * I_)            // 16384
#define PADCAP (16384 + E_ * 128)    // 20480, pad-to-128

typedef unsigned short u16;
using bf16x8_t = __attribute__((ext_vector_type(8))) __bf16;
using f32x4_t  = __attribute__((ext_vector_type(4))) float;

__device__ __forceinline__ u16 f2bf(float x) {
  union { float f; uint32_t u; } v; v.f = x;
  uint32_t u = v.u;
  uint32_t r = (u + 0x7fffu + ((u >> 16) & 1u)) >> 16;
  return (u16)r;
}
__device__ __forceinline__ float bf2f(u16 x) {
  union { uint32_t u; float f; } v; v.u = ((uint32_t)x) << 16; return v.f;
}

__device__ __forceinline__ void load_lds16(const void* g, void* l) {
  __builtin_amdgcn_global_load_lds(
      (const __attribute__((address_space(1))) unsigned int*)g,
      (__attribute__((address_space(3))) unsigned int*)l,
      16, 0, 0);
}

// u16-element offsets inside wbf: [bg | bu | bd | bshg | bshu | bshd]
#define OFF_BU   16777216L
#define OFF_BD   33554432L
#define OFF_BSHG 50331648L
#define OFF_BSHU 51380224L
#define OFF_BSHD 52428800L
#define WBF_TOT  53477376L

// ---------------- prep: init + gw transpose + all-weight f32->bf16 ----------
#define W4_WG  4194304L
#define W4_WU  8388608L
#define W4_WD  12582912L
#define W4_SHG 12845056L
#define W4_SHU 13107200L
#define W4_TOT 13369344L
__global__ void prep_kernel(const float* __restrict__ gw, float* __restrict__ gwT,
                            int* __restrict__ counts, int* __restrict__ cursor,
                            int* __restrict__ qheads,
                            int* __restrict__ tok_list, float* __restrict__ wt_list,
                            const float* __restrict__ wg, const float* __restrict__ wu,
                            const float* __restrict__ wd, const float* __restrict__ shg,
                            const float* __restrict__ shu, const float* __restrict__ shd,
                            u16* __restrict__ wbf) {
  long i0 = (long)blockIdx.x * blockDim.x + threadIdx.x;
  if (i0 < H_ * E_) {
    int k = (int)(i0 >> 5), e = (int)(i0 & 31);
    gwT[i0] = gw[(long)e * H_ + k];
  }
  if (i0 < PADCAP) { tok_list[i0] = 0; wt_list[i0] = 0.f; }
  if (i0 < E_) { counts[i0] = 0; cursor[i0] = 0; }
  if (i0 < 2) qheads[i0] = 0;

  long stride = (long)gridDim.x * blockDim.x;
  for (long i = i0; i < W4_TOT; i += stride) {
    const float* s; long off; long dofs;
    if (i < W4_WG)       { s = wg;  off = i;            dofs = off * 4; }
    else if (i < W4_WU)  { s = wu;  off = i - W4_WG;    dofs = OFF_BU + off * 4; }
    else if (i < W4_WD)  { s = wd;  off = i - W4_WU;    dofs = OFF_BD + off * 4; }
    else if (i < W4_SHG) { s = shg; off = i - W4_WD;    dofs = OFF_BSHG + off * 4; }
    else if (i < W4_SHU) { s = shu; off = i - W4_SHG;   dofs = OFF_BSHU + off * 4; }
    else                 { s = shd; off = i - W4_SHU;   dofs = OFF_BSHD + off * 4; }
    float4 v = ((const float4*)s)[off];
    ushort4 o;
    o.x = f2bf(v.x); o.y = f2bf(v.y); o.z = f2bf(v.z); o.w = f2bf(v.w);
    *(ushort4*)(wbf + dofs) = o;
  }
}

// ---------------- logits: split-K partials + hs->bf16 -----------------------
__global__ __launch_bounds__(256) void logits_kernel(
    const float* __restrict__ h, const float* __restrict__ gwT,
    float* __restrict__ lpart,   // [8][T][E]
    u16* __restrict__ hbf, int T) {
  __shared__ float shh[64][128];
  __shared__ float shw[128][E_];
  const int tid = threadIdx.x;
  const int t0 = blockIdx.x * 64;
  const int k0 = blockIdx.y * 128;
  #pragma unroll
  for (int i = 0; i < 8; ++i) {
    int c = tid + 256 * i;
    int row = c >> 5, col = c & 31;
    float4 v = *(const float4*)(h + (size_t)(t0 + row) * H_ + k0 + col * 4);
    *(float4*)(&shh[row][col * 4]) = v;
    ushort4 o;
    o.x = f2bf(v.x); o.y = f2bf(v.y); o.z = f2bf(v.z); o.w = f2bf(v.w);
    *(ushort4*)(hbf + (size_t)(t0 + row) * H_ + k0 + col * 4) = o;
  }
  #pragma unroll
  for (int i = 0; i < 4; ++i) {
    int c = tid + 256 * i;
    int row = c >> 3, col = c & 7;
    *(float4*)(&shw[row][col * 4]) =
        *(const float4*)(gwT + (size_t)(k0 + row) * E_ + col * 4);
  }
  __syncthreads();
  const int e = tid & 31;
  const int tb = (tid >> 5) * 8;
  float acc[8] = {0.f, 0.f, 0.f, 0.f, 0.f, 0.f, 0.f, 0.f};
  #pragma unroll 4
  for (int k = 0; k < 128; ++k) {
    float wv = shw[k][e];
    #pragma unroll
    for (int j = 0; j < 8; ++j) acc[j] += shh[tb + j][k] * wv;
  }
  #pragma unroll
  for (int j = 0; j < 8; ++j)
    lpart[((size_t)blockIdx.y * T + (t0 + tb + j)) * E_ + e] = acc[j];
}

// ---------------- topk: wave-parallel (lane=expert, half-wave=token) --------
__global__ __launch_bounds__(256) void topk_kernel(
    const float* __restrict__ lpart, const float* __restrict__ gb,
    int* __restrict__ idx8, float* __restrict__ wt8, int* __restrict__ counts,
    int T) {
  const int tid = threadIdx.x;
  const int l = tid & 63, wid = tid >> 6;
  const int e = l & 31, half = l >> 5;
  const int t = blockIdx.x * 8 + wid * 2 + half;

  float lg = 0.f;
  #pragma unroll
  for (int s = 0; s < 8; ++s) lg += lpart[((size_t)s * T + t) * E_ + e];
  float score = 1.f / (1.f + __expf(-lg));
  float sc = score + gb[e];

  float x1 = __shfl_xor(sc, 1);
  float x2 = __shfl_xor(sc, 2);
  float x3 = __shfl_xor(sc, 3);
  float hi1 = fmaxf(sc, x1), lo1 = fminf(sc, x1);
  float hi2 = fmaxf(x2, x3), lo2 = fminf(x2, x3);
  float m1 = fmaxf(hi1, hi2);
  float m2 = (hi1 >= hi2) ? fmaxf(lo1, hi2) : fmaxf(lo2, hi1);
  float gs = m1 + m2;

  float ga[8];
  #pragma unroll
  for (int g = 0; g < 8; ++g) ga[g] = __shfl(gs, (half << 5) + g * 4);
  unsigned gm = 0;
  #pragma unroll
  for (int r = 0; r < 4; ++r) {
    float bv = -1e30f; int bi = 0;
    #pragma unroll
    for (int g = 0; g < 8; ++g)
      if (!((gm >> g) & 1u) && ga[g] > bv) { bv = ga[g]; bi = g; }
    gm |= 1u << bi;
  }
  float msk = ((gm >> (e >> 2)) & 1u) ? sc : 0.f;

  float wsum = 0.f, myw = 0.f;
  int myi = 0;
  #pragma unroll
  for (int r = 0; r < 8; ++r) {
    float av = msk; int ai = e;
    #pragma unroll
    for (int m = 16; m; m >>= 1) {
      float ov = __shfl_xor(av, m);
      int oi = __shfl_xor(ai, m);
      if (ov > av || (ov == av && oi < ai)) { av = ov; ai = oi; }
    }
    float wscore = __shfl(score, (half << 5) + ai);
    wsum += wscore;
    if (e == r) { myi = ai; myw = wscore; }
    if (e == ai) msk = 0.f;
  }
  float inv = SCALE_ / (wsum + 1e-20f);
  if (e < 8) {
    idx8[(size_t)t * 8 + e] = myi;
    wt8[(size_t)t * 8 + e] = myw * inv;
    atomicAdd(&counts[myi], 1);
  }
}

// ---------------- fill (inline padded scan) ----------------
__global__ void fill_kernel(const int* __restrict__ idx8, const float* __restrict__ wt8,
                            const int* __restrict__ counts, int* __restrict__ cursor,
                            int* __restrict__ tok_list, float* __restrict__ wt_list,
                            int* __restrict__ pair_pos, int npair) {
  int i = blockIdx.x * blockDim.x + threadIdx.x;
  if (i >= npair) return;
  int e = idx8[i];
  int offz = 0;
  for (int k = 0; k < E_; ++k) {
    if (k == e) break;
    offz += ((counts[k] + 127) >> 7) << 7;
  }
  int p = atomicAdd(&cursor[e], 1);
  int slot = offz + p;
  tok_list[slot] = i >> 3;
  wt_list[slot] = wt8[i];
  pair_pos[i] = slot;
}

// ---------------- phase 1: persistent dual GEMM, 128x128, BK=32 -------------
// 3-buffer depth-2 pipeline with counted vmcnt (T4): per step, wait only the
// oldest stage (vmcnt(6)), raw s_barrier, compute, then issue stage s+2.
__global__ __launch_bounds__(256, 2) void p1_kernel(
    const u16* __restrict__ hbf,
    const u16* __restrict__ wbf,
    const int* __restrict__ counts,
    const int* __restrict__ tok_list, const float* __restrict__ wt_list,
    int* __restrict__ qheads,
    u16* __restrict__ gu,          // [PADCAP][512]
    u16* __restrict__ gu_sh,       // [T][1024]
    int T) {
  __shared__ u16 lsA[3][128 * 32];
  __shared__ u16 lsB0[3][128 * 32];
  __shared__ u16 lsB1[3][128 * 32];
  __shared__ int s_tok[128];
  __shared__ float s_wt[128];
  __shared__ int s_off[E_], s_ntt[E_];
  __shared__ int s_tot, s_tile;

  const int tid = threadIdx.x;
  if (tid == 0) {
    int run = 0, tot = 0;
    for (int e = 0; e < E_; ++e) {
      s_off[e] = run;
      int nt = (counts[e] + 127) >> 7;
      s_ntt[e] = nt;
      run += nt << 7;
      tot += nt * 4;
    }
    s_tot = tot + (T / 128) * 8;
  }

  const int w = tid >> 6, l = tid & 63;
  const int wr = w >> 1, wc = w & 1;
  const int lr = l & 15, lh = l >> 4;
  const int rdblk = (lh ^ ((lr >> 1) & 3)) << 3;

  const int c0 = tid, c1 = tid + 256;
  const int row0 = c0 >> 2, cb0 = c0 & 3, scb0 = cb0 ^ ((row0 >> 1) & 3);
  const int row1 = c1 >> 2, cb1 = c1 & 3, scb1 = cb1 ^ ((row1 >> 1) & 3);

  for (;;) {
    __syncthreads();
    if (tid == 0) s_tile = atomicAdd(&qheads[0], 1);
    __syncthreads();
    int q = s_tile;
    if (q >= s_tot) break;

    int z = 0, rem = q;
    for (; z < E_; ++z) { int t = s_ntt[z] * 4; if (rem < t) break; rem -= t; }
    const bool sh_e = (z == E_);
    int tt, nb;
    if (sh_e) { tt = rem >> 3; nb = rem & 7; }
    else      { tt = rem >> 2; nb = rem & 3; }
    const int off = sh_e ? 0 : s_off[z];

    if (tid < 128) {
      if (sh_e) { s_tok[tid] = tt * 128 + tid; s_wt[tid] = 1.0f; }
      else {
        int slot = off + tt * 128 + tid;
        s_tok[tid] = tok_list[slot];
        s_wt[tid] = wt_list[slot];
      }
    }
    __syncthreads();

    const u16* Bg = sh_e ? (wbf + OFF_BSHG + (size_t)(nb * 128) * H_)
                         : (wbf + ((size_t)z * I_ + nb * 128) * H_);
    const u16* Bu = sh_e ? (wbf + OFF_BSHU + (size_t)(nb * 128) * H_)
                         : (wbf + OFF_BU + ((size_t)z * I_ + nb * 128) * H_);
    const u16* A0 = hbf + (size_t)s_tok[row0] * H_ + scb0 * 8;
    const u16* A1 = hbf + (size_t)s_tok[row1] * H_ + scb1 * 8;

    f32x4_t acc0[4][4], acc1[4][4];
    #pragma unroll
    for (int m = 0; m < 4; ++m)
      #pragma unroll
      for (int n = 0; n < 4; ++n) {
        acc0[m][n] = (f32x4_t){0.f, 0.f, 0.f, 0.f};
        acc1[m][n] = (f32x4_t){0.f, 0.f, 0.f, 0.f};
      }

    auto stage = [&](int b, int ks) {   // 6 loads / thread
      int k0 = ks * 32;
      load_lds16(A0 + k0, (char*)&lsA[b][0] + c0 * 16);
      load_lds16(A1 + k0, (char*)&lsA[b][0] + c1 * 16);
      load_lds16(Bg + (size_t)row0 * H_ + k0 + scb0 * 8, (char*)&lsB0[b][0] + c0 * 16);
      load_lds16(Bg + (size_t)row1 * H_ + k0 + scb1 * 8, (char*)&lsB0[b][0] + c1 * 16);
      load_lds16(Bu + (size_t)row0 * H_ + k0 + scb0 * 8, (char*)&lsB1[b][0] + c0 * 16);
      load_lds16(Bu + (size_t)row1 * H_ + k0 + scb1 * 8, (char*)&lsB1[b][0] + c1 * 16);
    };
    auto compute = [&](int b) {
      bf16x8_t af[4], b0f[4], b1f[4];
      #pragma unroll
      for (int m = 0; m < 4; ++m)
        af[m] = *(const bf16x8_t*)(&lsA[b][0] + (wr * 64 + m * 16 + lr) * 32 + rdblk);
      #pragma unroll
      for (int n = 0; n < 4; ++n) {
        b0f[n] = *(const bf16x8_t*)(&lsB0[b][0] + (wc * 64 + n * 16 + lr) * 32 + rdblk);
        b1f[n] = *(const bf16x8_t*)(&lsB1[b][0] + (wc * 64 + n * 16 + lr) * 32 + rdblk);
      }
      #pragma unroll
      for (int m = 0; m < 4; ++m)
        #pragma unroll
        for (int n = 0; n < 4; ++n) {
          acc0[m][n] = __builtin_amdgcn_mfma_f32_16x16x32_bf16(af[m], b0f[n], acc0[m][n], 0, 0, 0);
          acc1[m][n] = __builtin_amdgcn_mfma_f32_16x16x32_bf16(af[m], b1f[n], acc1[m][n], 0, 0, 0);
        }
    };

    stage(0, 0);
    stage(1, 1);
    int b0 = 0, b1 = 1, b2 = 2;
    #pragma unroll 1
    for (int s = 0; s < 31; ++s) {
      asm volatile("s_waitcnt vmcnt(6)" ::: "memory");
      __builtin_amdgcn_s_barrier();
      compute(b0);
      if (s < 30) stage(b2, s + 2);
      int tb = b0; b0 = b1; b1 = b2; b2 = tb;
    }
    asm volatile("s_waitcnt vmcnt(0)" ::: "memory");
    __builtin_amdgcn_s_barrier();
    compute(b0);

    const int ldo = sh_e ? (I_ * NSH_) : I_;
    u16* outp = sh_e ? (gu_sh + (size_t)(tt * 128) * ldo + nb * 128)
                     : (gu + (size_t)(off + tt * 128) * ldo + nb * 128);
    #pragma unroll
    for (int m = 0; m < 4; ++m) {
      #pragma unroll
      for (int n = 0; n < 4; ++n) {
        int col = wc * 64 + n * 16 + lr;
        #pragma unroll
        for (int j = 0; j < 4; ++j) {
          int trow = wr * 64 + m * 16 + lh * 4 + j;
          float gv = acc0[m][n][j], uv = acc1[m][n][j];
          float sv = gv / (1.f + __expf(-gv));
          outp[(size_t)trow * ldo + col] = f2bf(sv * uv * s_wt[trow]);
        }
      }
    }
  }
}

// ---------------- phase 2: persistent GEMM (down), 128x128, BK=32 -----------
// Same 3-buffer depth-2 counted-vmcnt pipeline (4 loads/thread -> vmcnt(4)).
__global__ __launch_bounds__(256, 3) void p2_kernel(
    const u16* __restrict__ gu, const u16* __restrict__ gu_sh,
    const u16* __restrict__ wbf,
    const int* __restrict__ counts,
    int* __restrict__ qheads,
    u16* __restrict__ part,        // [PADCAP][H]
    u16* __restrict__ part_sh,     // [T][H]
    int T) {
  __shared__ u16 lsA[3][128 * 32];
  __shared__ u16 lsB[3][128 * 32];
  __shared__ int s_off[E_], s_ntt[E_];
  __shared__ int s_tot, s_tile;

  const int tid = threadIdx.x;
  if (tid == 0) {
    int run = 0, tot = 0;
    for (int e = 0; e < E_; ++e) {
      s_off[e] = run;
      int nt = (counts[e] + 127) >> 7;
      s_ntt[e] = nt;
      run += nt << 7;
      tot += nt * 8;
    }
    s_tot = tot + (T / 128) * 8;
  }

  const int w = tid >> 6, l = tid & 63;
  const int wr = w >> 1, wc = w & 1;
  const int lr = l & 15, lh = l >> 4;
  const int rdblk = (lh ^ ((lr >> 1) & 3)) << 3;

  const int c0 = tid, c1 = tid + 256;
  const int row0 = c0 >> 2, cb0 = c0 & 3, scb0 = cb0 ^ ((row0 >> 1) & 3);
  const int row1 = c1 >> 2, cb1 = c1 & 3, scb1 = cb1 ^ ((row1 >> 1) & 3);

  for (;;) {
    __syncthreads();
    if (tid == 0) s_tile = atomicAdd(&qheads[1], 1);
    __syncthreads();
    int q = s_tile;
    if (q >= s_tot) break;

    int z = 0, rem = q;
    for (; z < E_; ++z) { int t = s_ntt[z] * 8; if (rem < t) break; rem -= t; }
    const bool sh_e = (z == E_);
    int tt = rem >> 3, nb = rem & 7;

    const int K = sh_e ? (I_ * NSH_) : I_;
    const int NT = K / 32;
    const u16* Ab = sh_e ? (gu_sh + (size_t)(tt * 128) * K)
                         : (gu + (size_t)(s_off[z] + tt * 128) * K);
    const u16* Bb = sh_e ? (wbf + OFF_BSHD + (size_t)(nb * 128) * K)
                         : (wbf + OFF_BD + (size_t)z * H_ * I_ + (size_t)(nb * 128) * K);
    u16* outp = sh_e ? (part_sh + (size_t)(tt * 128) * H_ + nb * 128)
                     : (part + (size_t)(s_off[z] + tt * 128) * H_ + nb * 128);

    f32x4_t acc[4][4];
    #pragma unroll
    for (int m = 0; m < 4; ++m)
      #pragma unroll
      for (int n = 0; n < 4; ++n) acc[m][n] = (f32x4_t){0.f, 0.f, 0.f, 0.f};

    auto stage = [&](int b, int ks) {   // 4 loads / thread
      int k0 = ks * 32;
      load_lds16(Ab + (size_t)row0 * K + k0 + scb0 * 8, (char*)&lsA[b][0] + c0 * 16);
      load_lds16(Ab + (size_t)row1 * K + k0 + scb1 * 8, (char*)&lsA[b][0] + c1 * 16);
      load_lds16(Bb + (size_t)row0 * K + k0 + scb0 * 8, (char*)&lsB[b][0] + c0 * 16);
      load_lds16(Bb + (size_t)row1 * K + k0 + scb1 * 8, (char*)&lsB[b][0] + c1 * 16);
    };
    auto compute = [&](int b) {
      bf16x8_t af[4], bf[4];
      #pragma unroll
      for (int m = 0; m < 4; ++m)
        af[m] = *(const bf16x8_t*)(&lsA[b][0] + (wr * 64 + m * 16 + lr) * 32 + rdblk);
      #pragma unroll
      for (int n = 0; n < 4; ++n)
        bf[n] = *(const bf16x8_t*)(&lsB[b][0] + (wc * 64 + n * 16 + lr) * 32 + rdblk);
      #pragma unroll
      for (int m = 0; m < 4; ++m)
        #pragma unroll
        for (int n = 0; n < 4; ++n)
          acc[m][n] = __builtin_amdgcn_mfma_f32_16x16x32_bf16(af[m], bf[n], acc[m][n], 0, 0, 0);
    };

    stage(0, 0);
    stage(1, 1);
    int b0 = 0, b1 = 1, b2 = 2;
    #pragma unroll 1
    for (int s = 0; s < NT - 1; ++s) {
      asm volatile("s_waitcnt vmcnt(4)" ::: "memory");
      __builtin_amdgcn_s_barrier();
      compute(b0);
      if (s + 2 < NT) stage(b2, s + 2);
      int tb = b0; b0 = b1; b1 = b2; b2 = tb;
    }
    asm volatile("s_waitcnt vmcnt(0)" ::: "memory");
    __builtin_amdgcn_s_barrier();
    compute(b0);

    #pragma unroll
    for (int m = 0; m < 4; ++m) {
      #pragma unroll
      for (int n = 0; n < 4; ++n) {
        int col = wc * 64 + n * 16 + lr;
        #pragma unroll
        for (int j = 0; j < 4; ++j) {
          int trow = wr * 64 + m * 16 + lh * 4 + j;
          outp[(size_t)trow * H_ + col] = f2bf(acc[m][n][j]);
        }
      }
    }
  }
}

// ---------------- combine ----------------
__global__ void combine_kernel(const u16* __restrict__ part, const u16* __restrict__ part_sh,
                               const int* __restrict__ pair_pos, float* __restrict__ out) {
  int t = blockIdx.x;
  int h = threadIdx.x * 4;
  int pp[8];
  #pragma unroll
  for (int s = 0; s < 8; ++s) pp[s] = pair_pos[(long)t * 8 + s];
  ushort4 v = *(const ushort4*)(part_sh + (size_t)t * H_ + h);
  float a0 = bf2f(v.x), a1 = bf2f(v.y), a2 = bf2f(v.z), a3 = bf2f(v.w);
  #pragma unroll
  for (int s = 0; s < 8; ++s) {
    ushort4 u = *(const ushort4*)(part + (size_t)pp[s] * H_ + h);
    a0 += bf2f(u.x); a1 += bf2f(u.y); a2 += bf2f(u.z); a3 += bf2f(u.w);
  }
  float4 o = {a0, a1, a2, a3};
  *(float4*)(out + (size_t)t * H_ + h) = o;
}

extern "C" void kernel_launch(void* const* d_in, const int* in_sizes, int n_in,
                              void* d_out, int out_size, void* d_ws, size_t ws_size,
                              hipStream_t stream) {
  const float* hs  = (const float*)d_in[0];
  const float* gw  = (const float*)d_in[1];
  const float* gb  = (const float*)d_in[2];
  const float* wg  = (const float*)d_in[3];
  const float* wu  = (const float*)d_in[4];
  const float* wd  = (const float*)d_in[5];
  const float* shg = (const float*)d_in[6];
  const float* shu = (const float*)d_in[7];
  const float* shd = (const float*)d_in[8];
  float* out = (float*)d_out;

  const int T = in_sizes[0] / H_;  // 2048

  char* ws = (char*)d_ws;
  size_t off = 0;
  auto alloc = [&](size_t bytes) {
    char* p = ws + off;
    off += (bytes + 255) & ~(size_t)255;
    return p;
  };
  int*   counts   = (int*)alloc(E_ * 4);
  int*   cursor   = (int*)alloc(E_ * 4);
  int*   qheads   = (int*)alloc(2 * 4);
  int*   idx8     = (int*)alloc((size_t)T * 8 * 4);
  float* wt8      = (float*)alloc((size_t)T * 8 * 4);
  int*   pair_pos = (int*)alloc((size_t)T * 8 * 4);
  int*   tok_list = (int*)alloc(PADCAP * 4);
  float* wt_list  = (float*)alloc(PADCAP * 4);
  float* gwT      = (float*)alloc((size_t)H_ * E_ * 4);
  float* lpart    = (float*)alloc((size_t)8 * T * E_ * 4);
  u16* hbf     = (u16*)alloc((size_t)T * H_ * 2);
  u16* wbf     = (u16*)alloc((size_t)WBF_TOT * 2);
  u16* gu      = (u16*)alloc((size_t)PADCAP * I_ * 2);
  u16* gu_sh   = (u16*)alloc((size_t)T * I_ * NSH_ * 2);
  u16* part    = (u16*)alloc((size_t)PADCAP * H_ * 2);
  u16* part_sh = (u16*)alloc((size_t)T * H_ * 2);
  if (off > ws_size) return;

  hipLaunchKernelGGL(prep_kernel, dim3(4096), dim3(256), 0, stream,
                     gw, gwT, counts, cursor, qheads, tok_list, wt_list,
                     wg, wu, wd, shg, shu, shd, wbf);

  hipLaunchKernelGGL(logits_kernel, dim3(T / 64, 8), dim3(256), 0, stream,
                     hs, gwT, lpart, hbf, T);

  hipLaunchKernelGGL(topk_kernel, dim3(T / 8), dim3(256), 0, stream,
                     lpart, gb, idx8, wt8, counts, T);

  hipLaunchKernelGGL(fill_kernel, dim3((T * 8 + 255) / 256), dim3(256), 0, stream,
                     idx8, wt8, counts, cursor, tok_list, wt_list, pair_pos, T * 8);

  hipLaunchKernelGGL(p1_kernel, dim3(512), dim3(256), 0, stream,
                     hbf, wbf, counts, tok_list, wt_list, qheads, gu, gu_sh, T);

  hipLaunchKernelGGL(p2_kernel, dim3(768), dim3(256), 0, stream,
                     gu, gu_sh, wbf, counts, qheads, part, part_sh, T);

  hipLaunchKernelGGL(combine_kernel, dim3(T), dim3(256), 0, stream,
                     part, part_sh, pair_pos, out);
}